// Round 1
// baseline (1063.033 us; speedup 1.0000x reference)
//
#include <hip/hip_runtime.h>

#define NSEG 15872
#define DD 129    // feature dim
#define HH 128    // hidden dim
#define EB 8      // edge batch per iteration

// ---------------------------------------------------------------------------
// Exclusive prefix sum of neighborhood_sizes -> offs[N+1]
// ---------------------------------------------------------------------------
__global__ __launch_bounds__(256) void scan_kernel(const int* __restrict__ sizes,
                                                   int* __restrict__ offs, int n) {
  __shared__ int sums[256];
  __shared__ int pref[256];
  const int t = threadIdx.x;
  const int chunk = (n + 255) >> 8;
  const int s0 = t * chunk;
  const int s1 = min(s0 + chunk, n);
  int s = 0;
  for (int i = s0; i < s1; ++i) s += sizes[i];
  sums[t] = s;
  __syncthreads();
  if (t == 0) {
    int acc = 0;
    for (int i = 0; i < 256; ++i) { pref[i] = acc; acc += sums[i]; }
  }
  __syncthreads();
  int acc = pref[t];
  for (int i = s0; i < s1; ++i) { offs[i] = acc; acc += sizes[i]; }
  if (t == 255) offs[n] = acc;
}

// ---------------------------------------------------------------------------
// One workgroup (128 threads) per segment. Fused: gather -> L1 -> L2 ->
// segment max -> Wo + residual -> (FINAL: 129->64->1 head).
// main-row contribution to layer 1 is computed once per segment (hm).
// ---------------------------------------------------------------------------
template <int FINAL>
__global__ __launch_bounds__(128) void block_kernel(
    const float* __restrict__ interpIn, float* __restrict__ interpOut,
    const float* __restrict__ addInfo, const int* __restrict__ nbrIdx,
    const int* __restrict__ offs,
    const float* __restrict__ W1, const float* __restrict__ b1,
    const float* __restrict__ W2, const float* __restrict__ b2,
    const float* __restrict__ Wo, const float* __restrict__ bo,
    const float* __restrict__ fW1, const float* __restrict__ fb1,
    const float* __restrict__ fW2, const float* __restrict__ fb2,
    float* __restrict__ finalOut) {
  const int seg = blockIdx.x;
  const int j = threadIdx.x;  // 0..127 : hidden feature

  __shared__ float mainrow[DD];
  __shared__ __align__(16) float nbrT[DD][12];  // [k][b], stride 12 for 16B align
  __shared__ __align__(16) float h1T[HH][12];
  __shared__ float iouS[EB];
  __shared__ float pooledS[HH];
  __shared__ float resrow[DD];

  const int e0 = offs[seg];
  const int e1 = offs[seg + 1];
  const long base = (long)seg * DD;

  for (int t = j; t < DD; t += 128) mainrow[t] = interpIn[base + t];
  __syncthreads();

  // per-segment invariant parts of layer 1
  const float wiou = W1[258 * HH + j];
  float hm = b1[j];
#pragma unroll 3
  for (int k = 0; k < DD; ++k) hm = fmaf(mainrow[k], W1[(DD + k) * HH + j], hm);
  const float b2j = b2[j];

  float pooled = 0.0f;  // relu output >= 0, so 0-init == segment max

  for (int e = e0; e < e1; e += EB) {
    const int nb = min(EB, e1 - e);
    // gather neighbor rows (transposed into LDS)
#pragma unroll
    for (int b = 0; b < EB; ++b) {
      const int ee = (b < nb) ? (e + b) : e0;  // e0 always valid (size>=1)
      const long nbase = (long)nbrIdx[ee] * DD;
      for (int t = j; t < DD; t += 128) nbrT[t][b] = interpIn[nbase + t];
    }
    if (j < EB) iouS[j] = addInfo[(j < nb) ? (e + j) : e0];
    __syncthreads();

    // layer 1: a[b] = sum_k nbr[b][k] * W1[k][j]
    float a[EB];
#pragma unroll
    for (int b = 0; b < EB; ++b) a[b] = 0.f;
#pragma unroll 3
    for (int k = 0; k < DD; ++k) {
      const float w = W1[k * HH + j];
      const float4 x0 = *(const float4*)&nbrT[k][0];
      const float4 x1 = *(const float4*)&nbrT[k][4];
      a[0] = fmaf(x0.x, w, a[0]); a[1] = fmaf(x0.y, w, a[1]);
      a[2] = fmaf(x0.z, w, a[2]); a[3] = fmaf(x0.w, w, a[3]);
      a[4] = fmaf(x1.x, w, a[4]); a[5] = fmaf(x1.y, w, a[5]);
      a[6] = fmaf(x1.z, w, a[6]); a[7] = fmaf(x1.w, w, a[7]);
    }
#pragma unroll
    for (int b = 0; b < EB; ++b)
      h1T[j][b] = fmaxf(fmaf(wiou, iouS[b], a[b] + hm), 0.f);
    __syncthreads();

    // layer 2: c[b] = b2 + sum_k h1[b][k] * W2[k][j]
    float c[EB];
#pragma unroll
    for (int b = 0; b < EB; ++b) c[b] = b2j;
#pragma unroll 4
    for (int k = 0; k < HH; ++k) {
      const float w = W2[k * HH + j];
      const float4 y0 = *(const float4*)&h1T[k][0];
      const float4 y1 = *(const float4*)&h1T[k][4];
      c[0] = fmaf(y0.x, w, c[0]); c[1] = fmaf(y0.y, w, c[1]);
      c[2] = fmaf(y0.z, w, c[2]); c[3] = fmaf(y0.w, w, c[3]);
      c[4] = fmaf(y1.x, w, c[4]); c[5] = fmaf(y1.y, w, c[5]);
      c[6] = fmaf(y1.z, w, c[6]); c[7] = fmaf(y1.w, w, c[7]);
    }
#pragma unroll
    for (int b = 0; b < EB; ++b)
      if (b < nb) pooled = fmaxf(pooled, fmaxf(c[b], 0.f));
    __syncthreads();  // protect nbrT/h1T reuse next iteration
  }

  pooledS[j] = pooled;
  __syncthreads();

  // block output + residual: res[j] = main[j] + bo[j] + pooled . Wo[:,j]
  float accO = bo[j];
#pragma unroll 4
  for (int k = 0; k < HH; ++k) accO = fmaf(pooledS[k], Wo[k * DD + j], accO);
  const float res = mainrow[j] + accO;
  resrow[j] = res;
  if (!FINAL) interpOut[base + j] = res;

  // column 128 via wave 0 reduction
  if (j < 64) {
    float p = pooledS[j] * Wo[j * DD + 128] +
              pooledS[j + 64] * Wo[(j + 64) * DD + 128];
#pragma unroll
    for (int o = 32; o > 0; o >>= 1) p += __shfl_down(p, o, 64);
    if (j == 0) {
      const float r128 = mainrow[128] + bo[128] + p;
      resrow[128] = r128;
      if (!FINAL) interpOut[base + 128] = r128;
    }
  }
  __syncthreads();

  if (FINAL) {
    if (j < 64) {
      float a = fb1[j];
#pragma unroll 3
      for (int k = 0; k < DD; ++k) a = fmaf(resrow[k], fW1[k * 64 + j], a);
      float v = fmaxf(a, 0.f) * fW2[j];
#pragma unroll
      for (int o = 32; o > 0; o >>= 1) v += __shfl_down(v, o, 64);
      if (j == 0) finalOut[seg] = v + fb2[0];
    }
  }
}

// ---------------------------------------------------------------------------
extern "C" void kernel_launch(void* const* d_in, const int* in_sizes, int n_in,
                              void* d_out, int out_size, void* d_ws, size_t ws_size,
                              hipStream_t stream) {
  const float* interp  = (const float*)d_in[0];
  const float* addInfo = (const float*)d_in[1];
  const int* sizes     = (const int*)d_in[2];
  const int* nbrIdx    = (const int*)d_in[3];
  // d_in[4] = self_indexes (implied by segment layout; unused)
  const float* b0W1 = (const float*)d_in[5];
  const float* b0b1 = (const float*)d_in[6];
  const float* b0W2 = (const float*)d_in[7];
  const float* b0b2 = (const float*)d_in[8];
  const float* b0Wo = (const float*)d_in[9];
  const float* b0bo = (const float*)d_in[10];
  const float* b1W1 = (const float*)d_in[11];
  const float* b1b1 = (const float*)d_in[12];
  const float* b1W2 = (const float*)d_in[13];
  const float* b1b2 = (const float*)d_in[14];
  const float* b1Wo = (const float*)d_in[15];
  const float* b1bo = (const float*)d_in[16];
  const float* fW1  = (const float*)d_in[17];
  const float* fb1  = (const float*)d_in[18];
  const float* fW2  = (const float*)d_in[19];
  const float* fb2  = (const float*)d_in[20];

  int* offs      = (int*)d_ws;                          // (N+1) ints
  float* interpB = (float*)((char*)d_ws + 65536);       // N x 129 fp32

  scan_kernel<<<1, 256, 0, stream>>>(sizes, offs, NSEG);

  block_kernel<0><<<NSEG, 128, 0, stream>>>(
      interp, interpB, addInfo, nbrIdx, offs,
      b0W1, b0b1, b0W2, b0b2, b0Wo, b0bo,
      nullptr, nullptr, nullptr, nullptr, nullptr);

  block_kernel<1><<<NSEG, 128, 0, stream>>>(
      interpB, nullptr, addInfo, nbrIdx, offs,
      b1W1, b1b1, b1W2, b1b2, b1Wo, b1bo,
      fW1, fb1, fW2, fb2, (float*)d_out);
}

// Round 2
// 576.702 us; speedup vs baseline: 1.8433x; 1.8433x over previous
//
#include <hip/hip_runtime.h>

#define NSEG 15872
#define DD 129
#define HH 128

typedef __attribute__((ext_vector_type(8))) short s16x8;
typedef __attribute__((ext_vector_type(4))) float f32x4;
typedef __attribute__((ext_vector_type(4))) unsigned short u16x4;

__device__ __forceinline__ unsigned short f2bf(float x) {
  union { float f; unsigned u; } c; c.f = x;
  unsigned r = c.u + 0x7FFFu + ((c.u >> 16) & 1u);
  return (unsigned short)(r >> 16);
}
__device__ __forceinline__ float bf2f(unsigned short v) {
  union { unsigned u; float f; } c; c.u = ((unsigned)v) << 16; return c.f;
}

// ---------------------------------------------------------------------------
// offs[N+1] = exclusive scan of sizes
// ---------------------------------------------------------------------------
__global__ __launch_bounds__(256) void scan_kernel(const int* __restrict__ sizes,
                                                   int* __restrict__ offs, int n) {
  __shared__ int sums[256];
  __shared__ int pref[256];
  const int t = threadIdx.x;
  const int chunk = (n + 255) >> 8;
  const int s0 = t * chunk, s1 = min(s0 + chunk, n);
  int s = 0;
  for (int i = s0; i < s1; ++i) s += sizes[i];
  sums[t] = s;
  __syncthreads();
  if (t == 0) { int a = 0; for (int i = 0; i < 256; ++i) { pref[i] = a; a += sums[i]; } }
  __syncthreads();
  int a = pref[t];
  for (int i = s0; i < s1; ++i) { offs[i] = a; a += sizes[i]; }
  if (t == 255) offs[n] = a;
}

// ---------------------------------------------------------------------------
// Pack W1 (nbr half, K padded 129->160) and W2 into MFMA B-frag layout bf16:
// PB[ks][lk][n][i] = W[ks*32+lk*8+i][n]   (zero for padded rows)
// PB1: per block 5*4*128*8 = 20480 shorts; PB2: per block 4*4*128*8 = 16384.
// ---------------------------------------------------------------------------
__global__ __launch_bounds__(256) void wprep_kernel(
    const float* __restrict__ W1b0, const float* __restrict__ W1b1,
    const float* __restrict__ W2b0, const float* __restrict__ W2b1,
    short* __restrict__ PB1, short* __restrict__ PB2) {
  const int id = blockIdx.x * 256 + threadIdx.x;
  if (id < 40960) {
    const int b = id / 20480, fI = id % 20480;
    const int i = fI & 7, nn = (fI >> 3) & 127, lk = (fI >> 10) & 3, ks = fI >> 12;
    const int row = ks * 32 + lk * 8 + i;
    const float* W = b ? W1b1 : W1b0;
    const float v = (row < DD) ? W[row * HH + nn] : 0.f;
    PB1[id] = (short)f2bf(v);
  } else if (id < 40960 + 32768) {
    const int f2 = id - 40960;
    const int fI = f2 % 16384;
    const int i = fI & 7, nn = (fI >> 3) & 127, lk = (fI >> 10) & 3, ks = fI >> 12;
    const int row = ks * 32 + lk * 8 + i;
    const float* W = (f2 >= 16384) ? W2b1 : W2b0;
    PB2[f2] = (short)f2bf(W[row * HH + nn]);
  }
}

// ---------------------------------------------------------------------------
// Per-node prep: bf16 padded table row (stride 160, zero pad) + Hm (fp32):
// Hm[n][j] = b1[j] + sum_k interp[n][k] * W1[(129+k)][j]
// ---------------------------------------------------------------------------
__global__ __launch_bounds__(128) void prep_kernel(
    const float* __restrict__ interp, const float* __restrict__ W1,
    const float* __restrict__ b1, unsigned short* __restrict__ tab,
    float* __restrict__ Hm) {
  __shared__ float row[DD];
  const int n = blockIdx.x, j = threadIdx.x;
  row[j] = interp[(long)n * DD + j];
  if (j == 0) row[128] = interp[(long)n * DD + 128];
  __syncthreads();
  unsigned short* tr = tab + (long)n * 160;
  tr[j] = f2bf(row[j]);
  if (j < 32) tr[128 + j] = (j == 0) ? f2bf(row[128]) : 0;
  float a = b1[j];
#pragma unroll 4
  for (int k = 0; k < DD; ++k) a = fmaf(row[k], W1[(DD + k) * HH + j], a);
  Hm[(long)n * HH + j] = a;
}

// ---------------------------------------------------------------------------
// GEMM1: H1 = relu(gather(tab,nbr) @ W1n + iou*wiou + Hm[self])  (bf16 out,
// row-major E x 128). One wave per 16-edge tile, grid-stride. B in registers.
// ---------------------------------------------------------------------------
__global__ __launch_bounds__(256) void gemm1_kernel(
    const unsigned short* __restrict__ tab, const short* __restrict__ PB1,
    const float* __restrict__ W1, const float* __restrict__ Hm,
    const float* __restrict__ iou, const int* __restrict__ nbrIdx,
    const int* __restrict__ selfIdx, unsigned short* __restrict__ H1,
    int ntiles, int E) {
  __shared__ __align__(16) float scratch[4][16 * 132];
  const int lane = threadIdx.x & 63;
  const int wslot = threadIdx.x >> 6;
  const int lk = lane >> 4;      // k-group / row-quad
  const int n16 = lane & 15;     // col-in-frag / A-row
  float* sc = scratch[wslot];

  s16x8 B[5][8];
  float wv[8];
#pragma unroll
  for (int ks = 0; ks < 5; ++ks)
#pragma unroll
    for (int nf = 0; nf < 8; ++nf)
      B[ks][nf] = *(const s16x8*)(PB1 + (((ks * 4 + lk) * 128) + nf * 16 + n16) * 8);
#pragma unroll
  for (int nf = 0; nf < 8; ++nf) wv[nf] = W1[258 * HH + nf * 16 + n16];

  const int wid = (blockIdx.x << 2) + wslot;
  const int nw = gridDim.x << 2;

  for (int tile = wid; tile < ntiles; tile += nw) {
    const int e0 = tile << 4;
    int er = e0 + n16; if (er >= E) er = E - 1;
    const unsigned short* arow = tab + (long)nbrIdx[er] * 160;
    s16x8 A[5];
#pragma unroll
    for (int ks = 0; ks < 5; ++ks)
      A[ks] = *(const s16x8*)(arow + ks * 32 + lk * 8);
    f32x4 C[8];
#pragma unroll
    for (int nf = 0; nf < 8; ++nf) C[nf] = (f32x4){0.f, 0.f, 0.f, 0.f};
#pragma unroll
    for (int ks = 0; ks < 5; ++ks)
#pragma unroll
      for (int nf = 0; nf < 8; ++nf)
        C[nf] = __builtin_amdgcn_mfma_f32_16x16x32_bf16(A[ks], B[ks][nf], C[nf], 0, 0, 0);
    float io[4];
    if (e0 + 16 <= E) {
      const f32x4 i4 = *(const f32x4*)(iou + e0 + lk * 4);
      io[0] = i4[0]; io[1] = i4[1]; io[2] = i4[2]; io[3] = i4[3];
    } else {
#pragma unroll
      for (int r = 0; r < 4; ++r) { int e = e0 + lk * 4 + r; io[r] = iou[e < E ? e : (E - 1)]; }
    }
    // C/D layout (col=lane&15, row=lk*4+r) -> LDS row-major (stride 132: 2-way
    // conflict only, free)
#pragma unroll
    for (int nf = 0; nf < 8; ++nf)
#pragma unroll
      for (int r = 0; r < 4; ++r)
        sc[(lk * 4 + r) * 132 + nf * 16 + n16] = C[nf][r] + io[r] * wv[nf];
    // read back row-major, add Hm[self], relu, bf16, store
#pragma unroll
    for (int s = 0; s < 4; ++s) {
      const int row = lk + (s << 2);
      const int e = e0 + row;
      const int seg = selfIdx[e < E ? e : (E - 1)];
      const float* hrow = Hm + (long)seg * HH + n16 * 8;
      const f32x4 h0 = *(const f32x4*)(sc + row * 132 + n16 * 8);
      const f32x4 h1 = *(const f32x4*)(sc + row * 132 + n16 * 8 + 4);
      const f32x4 m0 = *(const f32x4*)(hrow);
      const f32x4 m1 = *(const f32x4*)(hrow + 4);
      s16x8 o;
      o[0] = (short)f2bf(fmaxf(h0[0] + m0[0], 0.f));
      o[1] = (short)f2bf(fmaxf(h0[1] + m0[1], 0.f));
      o[2] = (short)f2bf(fmaxf(h0[2] + m0[2], 0.f));
      o[3] = (short)f2bf(fmaxf(h0[3] + m0[3], 0.f));
      o[4] = (short)f2bf(fmaxf(h1[0] + m1[0], 0.f));
      o[5] = (short)f2bf(fmaxf(h1[1] + m1[1], 0.f));
      o[6] = (short)f2bf(fmaxf(h1[2] + m1[2], 0.f));
      o[7] = (short)f2bf(fmaxf(h1[3] + m1[3], 0.f));
      *(s16x8*)(H1 + (long)(e0 + row) * HH + n16 * 8) = o;
    }
  }
}

// ---------------------------------------------------------------------------
// GEMM2: H2 = relu(H1 @ W2 + b2), stored bf16 in D-native blocked layout:
// H2[((tile*8+f)*256) + n16*16 + m]  (m = row in tile, j = f*16+n16)
// ---------------------------------------------------------------------------
__global__ __launch_bounds__(256) void gemm2_kernel(
    const unsigned short* __restrict__ H1, const short* __restrict__ PB2,
    const float* __restrict__ b2, unsigned short* __restrict__ H2, int ntiles) {
  const int lane = threadIdx.x & 63;
  const int lk = lane >> 4, n16 = lane & 15;
  s16x8 B[4][8];
  float bv[8];
#pragma unroll
  for (int ks = 0; ks < 4; ++ks)
#pragma unroll
    for (int nf = 0; nf < 8; ++nf)
      B[ks][nf] = *(const s16x8*)(PB2 + (((ks * 4 + lk) * 128) + nf * 16 + n16) * 8);
#pragma unroll
  for (int nf = 0; nf < 8; ++nf) bv[nf] = b2[nf * 16 + n16];

  const int wid = (blockIdx.x << 2) + (threadIdx.x >> 6);
  const int nw = gridDim.x << 2;
  for (int tile = wid; tile < ntiles; tile += nw) {
    const int e0 = tile << 4;
    s16x8 A[4];
#pragma unroll
    for (int ks = 0; ks < 4; ++ks)
      A[ks] = *(const s16x8*)(H1 + (long)(e0 + n16) * HH + ks * 32 + lk * 8);
    f32x4 C[8];
#pragma unroll
    for (int nf = 0; nf < 8; ++nf) C[nf] = (f32x4){0.f, 0.f, 0.f, 0.f};
#pragma unroll
    for (int ks = 0; ks < 4; ++ks)
#pragma unroll
      for (int nf = 0; nf < 8; ++nf)
        C[nf] = __builtin_amdgcn_mfma_f32_16x16x32_bf16(A[ks], B[ks][nf], C[nf], 0, 0, 0);
#pragma unroll
    for (int nf = 0; nf < 8; ++nf) {
      u16x4 o;
#pragma unroll
      for (int r = 0; r < 4; ++r) o[r] = f2bf(fmaxf(C[nf][r] + bv[nf], 0.f));
      *(u16x4*)(H2 + ((long)(tile * 8 + nf) << 8) + n16 * 16 + lk * 4) = o;
    }
  }
}

// ---------------------------------------------------------------------------
// Ragged segment-max over blocked H2 + Wo GEMM + residual (+ next-block prep
// or final head). One block (128 thr) per segment.
// ---------------------------------------------------------------------------
template <int FINAL>
__global__ __launch_bounds__(128) void segout_kernel(
    const unsigned short* __restrict__ H2, const int* __restrict__ offs,
    const float* __restrict__ resIn, const float* __restrict__ Wo,
    const float* __restrict__ bo, float* __restrict__ resOut,
    unsigned short* __restrict__ tab, const float* __restrict__ W1n,
    const float* __restrict__ b1n, float* __restrict__ HmOut,
    const float* __restrict__ fW1, const float* __restrict__ fb1,
    const float* __restrict__ fW2, const float* __restrict__ fb2,
    float* __restrict__ outFinal) {
  __shared__ float pooledS[HH];
  __shared__ float resS[DD];
  const int n = blockIdx.x, j = threadIdx.x;
  const int e0 = offs[n], e1 = offs[n + 1];
  const int f = j >> 4, n16 = j & 15;
  float p = 0.f;
  for (int e = e0; e < e1; ++e) {
    const int tile = e >> 4, m = e & 15;
    p = fmaxf(p, bf2f(H2[((long)(tile * 8 + f) << 8) + n16 * 16 + m]));
  }
  pooledS[j] = p;
  __syncthreads();
  float acc = bo[j];
#pragma unroll 4
  for (int k = 0; k < HH; ++k) acc = fmaf(pooledS[k], Wo[k * DD + j], acc);
  const float rj = resIn[(long)n * DD + j] + acc;
  resS[j] = rj;
  if (j < 64) {
    float pp = pooledS[j] * Wo[j * DD + 128] + pooledS[j + 64] * Wo[(j + 64) * DD + 128];
#pragma unroll
    for (int o = 32; o > 0; o >>= 1) pp += __shfl_down(pp, o, 64);
    if (j == 0) resS[128] = resIn[(long)n * DD + 128] + bo[128] + pp;
  }
  __syncthreads();
  if (!FINAL) {
    resOut[(long)n * DD + j] = resS[j];
    if (j == 0) resOut[(long)n * DD + 128] = resS[128];
    unsigned short* tr = tab + (long)n * 160;
    tr[j] = f2bf(resS[j]);
    if (j < 32) tr[128 + j] = (j == 0) ? f2bf(resS[128]) : 0;
    float a2 = b1n[j];
#pragma unroll 4
    for (int k = 0; k < DD; ++k) a2 = fmaf(resS[k], W1n[(DD + k) * HH + j], a2);
    HmOut[(long)n * HH + j] = a2;
  } else {
    if (j < 64) {
      float a = fb1[j];
#pragma unroll 4
      for (int k = 0; k < DD; ++k) a = fmaf(resS[k], fW1[k * 64 + j], a);
      float v = fmaxf(a, 0.f) * fW2[j];
#pragma unroll
      for (int o = 32; o > 0; o >>= 1) v += __shfl_down(v, o, 64);
      if (j == 0) outFinal[n] = v + fb2[0];
    }
  }
}

// ---------------------------------------------------------------------------
extern "C" void kernel_launch(void* const* d_in, const int* in_sizes, int n_in,
                              void* d_out, int out_size, void* d_ws, size_t ws_size,
                              hipStream_t stream) {
  const float* interp  = (const float*)d_in[0];
  const float* addInfo = (const float*)d_in[1];
  const int* sizes     = (const int*)d_in[2];
  const int* nbrIdx    = (const int*)d_in[3];
  const int* selfIdx   = (const int*)d_in[4];
  const float* b0W1 = (const float*)d_in[5];
  const float* b0b1 = (const float*)d_in[6];
  const float* b0W2 = (const float*)d_in[7];
  const float* b0b2 = (const float*)d_in[8];
  const float* b0Wo = (const float*)d_in[9];
  const float* b0bo = (const float*)d_in[10];
  const float* b1W1 = (const float*)d_in[11];
  const float* b1b1 = (const float*)d_in[12];
  const float* b1W2 = (const float*)d_in[13];
  const float* b1b2 = (const float*)d_in[14];
  const float* b1Wo = (const float*)d_in[15];
  const float* b1bo = (const float*)d_in[16];
  const float* fW1  = (const float*)d_in[17];
  const float* fb1  = (const float*)d_in[18];
  const float* fW2  = (const float*)d_in[19];
  const float* fb2  = (const float*)d_in[20];

  const int E = in_sizes[1];               // add_info is (E,1)
  const int ntiles = (E + 15) >> 4;

  // workspace layout (bytes)
  char* ws = (char*)d_ws;
  int*            offs = (int*)(ws + 0);                   //  65536
  short*          PB1  = (short*)(ws + 65536);             //  81920 (2 blocks)
  short*          PB2  = (short*)(ws + 147456);            //  65536 (2 blocks)
  unsigned short* TAB  = (unsigned short*)(ws + 212992);   //  N*160*2 = 5079040
  float*          HM   = (float*)(ws + 5292032);           //  N*128*4 = 8126464
  unsigned short* H1   = (unsigned short*)(ws + 13418496); //  ntiles*16*128*2
  unsigned short* H2   = (unsigned short*)(ws + 78430208); //  same
  float*          POOL_RES = (float*)(ws + 143441920);     //  N*129*4 (res0)
  (void)POOL_RES;
  float*          RES  = (float*)(ws + 143441920);

  scan_kernel<<<1, 256, 0, stream>>>(sizes, offs, NSEG);
  wprep_kernel<<<288, 256, 0, stream>>>(b0W1, b1W1, b0W2, b1W2, PB1, PB2);
  prep_kernel<<<NSEG, 128, 0, stream>>>(interp, b0W1, b0b1, TAB, HM);

  // ---- block 0 ----
  gemm1_kernel<<<1024, 256, 0, stream>>>(TAB, PB1, b0W1, HM, addInfo, nbrIdx,
                                         selfIdx, H1, ntiles, E);
  gemm2_kernel<<<1024, 256, 0, stream>>>(H1, PB2, b0b2, H2, ntiles);
  segout_kernel<0><<<NSEG, 128, 0, stream>>>(
      H2, offs, interp, b0Wo, b0bo, RES, TAB, b1W1, b1b1, HM,
      nullptr, nullptr, nullptr, nullptr, nullptr);

  // ---- block 1 ----
  gemm1_kernel<<<1024, 256, 0, stream>>>(TAB, PB1 + 20480, b1W1, HM, addInfo,
                                         nbrIdx, selfIdx, H1, ntiles, E);
  gemm2_kernel<<<1024, 256, 0, stream>>>(H1, PB2 + 16384, b1b2, H2, ntiles);
  segout_kernel<1><<<NSEG, 128, 0, stream>>>(
      H2, offs, RES, b1Wo, b1bo, nullptr, nullptr, nullptr, nullptr, nullptr,
      fW1, fb1, fW2, fb2, (float*)d_out);
}

// Round 3
// 554.597 us; speedup vs baseline: 1.9168x; 1.0399x over previous
//
#include <hip/hip_runtime.h>

#define NSEG 15872
#define DD 129
#define HH 128

typedef __attribute__((ext_vector_type(8))) short s16x8;
typedef __attribute__((ext_vector_type(4))) float f32x4;

__device__ __forceinline__ unsigned short f2bf(float x) {
  union { float f; unsigned u; } c; c.f = x;
  unsigned r = c.u + 0x7FFFu + ((c.u >> 16) & 1u);
  return (unsigned short)(r >> 16);
}

// ---------------------------------------------------------------------------
// offs[N+1] = exclusive scan of sizes
// ---------------------------------------------------------------------------
__global__ __launch_bounds__(256) void scan_kernel(const int* __restrict__ sizes,
                                                   int* __restrict__ offs, int n) {
  __shared__ int sums[256];
  __shared__ int pref[256];
  const int t = threadIdx.x;
  const int chunk = (n + 255) >> 8;
  const int s0 = t * chunk, s1 = min(s0 + chunk, n);
  int s = 0;
  for (int i = s0; i < s1; ++i) s += sizes[i];
  sums[t] = s;
  __syncthreads();
  if (t == 0) { int a = 0; for (int i = 0; i < 256; ++i) { pref[i] = a; a += sums[i]; } }
  __syncthreads();
  int a = pref[t];
  for (int i = s0; i < s1; ++i) { offs[i] = a; a += sizes[i]; }
  if (t == 255) offs[n] = a;
}

// ---------------------------------------------------------------------------
// Pack W1 (nbr half, K padded 129->160) and W2 into MFMA B-frag layout bf16.
// ---------------------------------------------------------------------------
__global__ __launch_bounds__(256) void wprep_kernel(
    const float* __restrict__ W1b0, const float* __restrict__ W1b1,
    const float* __restrict__ W2b0, const float* __restrict__ W2b1,
    short* __restrict__ PB1, short* __restrict__ PB2) {
  const int id = blockIdx.x * 256 + threadIdx.x;
  if (id < 40960) {
    const int b = id / 20480, fI = id % 20480;
    const int i = fI & 7, nn = (fI >> 3) & 127, lk = (fI >> 10) & 3, ks = fI >> 12;
    const int row = ks * 32 + lk * 8 + i;
    const float* W = b ? W1b1 : W1b0;
    const float v = (row < DD) ? W[row * HH + nn] : 0.f;
    PB1[id] = (short)f2bf(v);
  } else if (id < 40960 + 32768) {
    const int f2 = id - 40960;
    const int fI = f2 % 16384;
    const int i = fI & 7, nn = (fI >> 3) & 127, lk = (fI >> 10) & 3, ks = fI >> 12;
    const int row = ks * 32 + lk * 8 + i;
    const float* W = (f2 >= 16384) ? W2b1 : W2b0;
    PB2[f2] = (short)f2bf(W[row * HH + nn]);
  }
}

// ---------------------------------------------------------------------------
// Per-node prep: bf16 padded table row (stride 160) + Hm fp32.
// ---------------------------------------------------------------------------
__global__ __launch_bounds__(128) void prep_kernel(
    const float* __restrict__ interp, const float* __restrict__ W1,
    const float* __restrict__ b1, unsigned short* __restrict__ tab,
    float* __restrict__ Hm) {
  __shared__ float row[DD];
  const int n = blockIdx.x, j = threadIdx.x;
  row[j] = interp[(long)n * DD + j];
  if (j == 0) row[128] = interp[(long)n * DD + 128];
  __syncthreads();
  unsigned short* tr = tab + (long)n * 160;
  tr[j] = f2bf(row[j]);
  if (j < 32) tr[128 + j] = (j == 0) ? f2bf(row[128]) : 0;
  float a = b1[j];
#pragma unroll 4
  for (int k = 0; k < DD; ++k) a = fmaf(row[k], W1[(DD + k) * HH + j], a);
  Hm[(long)n * HH + j] = a;
}

// ---------------------------------------------------------------------------
// GEMM1: H1 = relu(gather(tab,nbr) @ W1n + iou*wiou + Hm[self])  (bf16,
// row-major E x 128). One wave per 16-edge dense tile, grid-stride.
// ---------------------------------------------------------------------------
__global__ __launch_bounds__(256) void gemm1_kernel(
    const unsigned short* __restrict__ tab, const short* __restrict__ PB1,
    const float* __restrict__ W1, const float* __restrict__ Hm,
    const float* __restrict__ iou, const int* __restrict__ nbrIdx,
    const int* __restrict__ selfIdx, unsigned short* __restrict__ H1,
    int ntiles, int E) {
  __shared__ __align__(16) float scratch[4][16 * 132];
  const int lane = threadIdx.x & 63;
  const int wslot = threadIdx.x >> 6;
  const int lk = lane >> 4;
  const int n16 = lane & 15;
  float* sc = scratch[wslot];

  s16x8 B[5][8];
  float wv[8];
#pragma unroll
  for (int ks = 0; ks < 5; ++ks)
#pragma unroll
    for (int nf = 0; nf < 8; ++nf)
      B[ks][nf] = *(const s16x8*)(PB1 + (((ks * 4 + lk) * 128) + nf * 16 + n16) * 8);
#pragma unroll
  for (int nf = 0; nf < 8; ++nf) wv[nf] = W1[258 * HH + nf * 16 + n16];

  const int wid = (blockIdx.x << 2) + wslot;
  const int nw = gridDim.x << 2;

  for (int tile = wid; tile < ntiles; tile += nw) {
    const int e0 = tile << 4;
    int er = e0 + n16; if (er >= E) er = E - 1;
    const unsigned short* arow = tab + (long)nbrIdx[er] * 160;
    s16x8 A[5];
#pragma unroll
    for (int ks = 0; ks < 5; ++ks)
      A[ks] = *(const s16x8*)(arow + ks * 32 + lk * 8);
    f32x4 C[8];
#pragma unroll
    for (int nf = 0; nf < 8; ++nf) C[nf] = (f32x4){0.f, 0.f, 0.f, 0.f};
#pragma unroll
    for (int ks = 0; ks < 5; ++ks)
#pragma unroll
      for (int nf = 0; nf < 8; ++nf)
        C[nf] = __builtin_amdgcn_mfma_f32_16x16x32_bf16(A[ks], B[ks][nf], C[nf], 0, 0, 0);
    float io[4];
    if (e0 + 16 <= E) {
      const f32x4 i4 = *(const f32x4*)(iou + e0 + lk * 4);
      io[0] = i4[0]; io[1] = i4[1]; io[2] = i4[2]; io[3] = i4[3];
    } else {
#pragma unroll
      for (int r = 0; r < 4; ++r) { int e = e0 + lk * 4 + r; io[r] = iou[e < E ? e : (E - 1)]; }
    }
#pragma unroll
    for (int nf = 0; nf < 8; ++nf)
#pragma unroll
      for (int r = 0; r < 4; ++r)
        sc[(lk * 4 + r) * 132 + nf * 16 + n16] = C[nf][r] + io[r] * wv[nf];
#pragma unroll
    for (int s = 0; s < 4; ++s) {
      const int row = lk + (s << 2);
      const int e = e0 + row;
      const int seg = selfIdx[e < E ? e : (E - 1)];
      const float* hrow = Hm + (long)seg * HH + n16 * 8;
      const f32x4 h0 = *(const f32x4*)(sc + row * 132 + n16 * 8);
      const f32x4 h1 = *(const f32x4*)(sc + row * 132 + n16 * 8 + 4);
      const f32x4 m0 = *(const f32x4*)(hrow);
      const f32x4 m1 = *(const f32x4*)(hrow + 4);
      s16x8 o;
      o[0] = (short)f2bf(fmaxf(h0[0] + m0[0], 0.f));
      o[1] = (short)f2bf(fmaxf(h0[1] + m0[1], 0.f));
      o[2] = (short)f2bf(fmaxf(h0[2] + m0[2], 0.f));
      o[3] = (short)f2bf(fmaxf(h0[3] + m0[3], 0.f));
      o[4] = (short)f2bf(fmaxf(h1[0] + m1[0], 0.f));
      o[5] = (short)f2bf(fmaxf(h1[1] + m1[1], 0.f));
      o[6] = (short)f2bf(fmaxf(h1[2] + m1[2], 0.f));
      o[7] = (short)f2bf(fmaxf(h1[3] + m1[3], 0.f));
      *(s16x8*)(H1 + (long)(e0 + row) * HH + n16 * 8) = o;
    }
  }
}

// ---------------------------------------------------------------------------
// Fused GEMM2 + segment-max + Wo/residual (+ prep or final head).
// One wave per segment; segment-aligned 16-row tiles, padded rows replicate
// the last edge (harmless for max). No H2 / pooled materialization.
// ---------------------------------------------------------------------------
template <int FINAL>
__global__ __launch_bounds__(256) void fused2_kernel(
    const unsigned short* __restrict__ H1, const int* __restrict__ offs,
    const short* __restrict__ PB2, const float* __restrict__ b2,
    const float* __restrict__ Wo, const float* __restrict__ bo,
    const float* __restrict__ resIn, float* __restrict__ resOut,
    unsigned short* __restrict__ tab, const float* __restrict__ W1n,
    const float* __restrict__ b1n, float* __restrict__ HmOut,
    const float* __restrict__ fW1, const float* __restrict__ fb1,
    const float* __restrict__ fW2, const float* __restrict__ fb2,
    float* __restrict__ outFinal) {
  __shared__ float pooledS[4][HH];
  __shared__ float resS[4][136];
  const int lane = threadIdx.x & 63;
  const int w = threadIdx.x >> 6;
  const int lk = lane >> 4, n16 = lane & 15;
  const int seg = (blockIdx.x << 2) + w;

  s16x8 B[4][8];
  float bv[8];
#pragma unroll
  for (int ks = 0; ks < 4; ++ks)
#pragma unroll
    for (int nf = 0; nf < 8; ++nf)
      B[ks][nf] = *(const s16x8*)(PB2 + (((ks * 4 + lk) * 128) + nf * 16 + n16) * 8);
#pragma unroll
  for (int nf = 0; nf < 8; ++nf) bv[nf] = b2[nf * 16 + n16];

  const int e0 = offs[seg], e1 = offs[seg + 1];
  const int nt = (e1 - e0 + 15) >> 4;

  float pm[8];
#pragma unroll
  for (int nf = 0; nf < 8; ++nf) pm[nf] = 0.f;

  for (int t = 0; t < nt; ++t) {
    int e = e0 + (t << 4) + n16;
    if (e >= e1) e = e1 - 1;
    const unsigned short* hrow = H1 + (long)e * HH;
    s16x8 A[4];
#pragma unroll
    for (int ks = 0; ks < 4; ++ks)
      A[ks] = *(const s16x8*)(hrow + ks * 32 + lk * 8);
    f32x4 C[8];
#pragma unroll
    for (int nf = 0; nf < 8; ++nf) C[nf] = (f32x4){0.f, 0.f, 0.f, 0.f};
#pragma unroll
    for (int ks = 0; ks < 4; ++ks)
#pragma unroll
      for (int nf = 0; nf < 8; ++nf)
        C[nf] = __builtin_amdgcn_mfma_f32_16x16x32_bf16(A[ks], B[ks][nf], C[nf], 0, 0, 0);
#pragma unroll
    for (int nf = 0; nf < 8; ++nf) {
#pragma unroll
      for (int r = 0; r < 4; ++r) pm[nf] = fmaxf(pm[nf], C[nf][r] + bv[nf]);
    }
  }
  // max across lk groups (lanes sharing n16)
#pragma unroll
  for (int nf = 0; nf < 8; ++nf) {
    float p = pm[nf];
    p = fmaxf(p, __shfl_xor(p, 16, 64));
    p = fmaxf(p, __shfl_xor(p, 32, 64));
    pm[nf] = p;
  }
  if (lane < 16) {
#pragma unroll
    for (int nf = 0; nf < 8; ++nf) pooledS[w][nf * 16 + n16] = pm[nf];
  }
  __syncthreads();

  // Wo GEMM + residual (cols c0=lane, c1=lane+64; col 128 via reduction)
  const int c0 = lane, c1 = lane + 64;
  float o0 = bo[c0], o1 = bo[c1];
  float v128 = pooledS[w][lane] * Wo[lane * DD + 128] +
               pooledS[w][lane + 64] * Wo[(lane + 64) * DD + 128];
#pragma unroll 4
  for (int k = 0; k < HH; ++k) {
    const float p = pooledS[w][k];
    o0 = fmaf(p, Wo[k * DD + c0], o0);
    o1 = fmaf(p, Wo[k * DD + c1], o1);
  }
#pragma unroll
  for (int o = 32; o > 0; o >>= 1) v128 += __shfl_down(v128, o, 64);
  const long rb = (long)seg * DD;
  const float r0 = resIn[rb + c0] + o0;
  const float r1 = resIn[rb + c1] + o1;
  resS[w][c0] = r0;
  resS[w][c1] = r1;
  if (lane == 0) resS[w][128] = resIn[rb + 128] + bo[128] + v128;
  __syncthreads();

  if (!FINAL) {
    resOut[rb + c0] = r0;
    resOut[rb + c1] = r1;
    if (lane == 0) resOut[rb + 128] = resS[w][128];
    unsigned short* tr = tab + (long)seg * 160;
    tr[c0] = f2bf(r0);
    tr[c1] = f2bf(r1);
    if (lane == 0) tr[128] = f2bf(resS[w][128]);
    if (lane >= 1 && lane < 32) tr[128 + lane] = 0;
    float h0 = b1n[c0], h1 = b1n[c1];
#pragma unroll 4
    for (int k = 0; k < DD; ++k) {
      const float rk = resS[w][k];
      h0 = fmaf(rk, W1n[(DD + k) * HH + c0], h0);
      h1 = fmaf(rk, W1n[(DD + k) * HH + c1], h1);
    }
    HmOut[(long)seg * HH + c0] = h0;
    HmOut[(long)seg * HH + c1] = h1;
  } else {
    float a = fb1[lane];
#pragma unroll 4
    for (int k = 0; k < DD; ++k) a = fmaf(resS[w][k], fW1[k * 64 + lane], a);
    float v = fmaxf(a, 0.f) * fW2[lane];
#pragma unroll
    for (int o = 32; o > 0; o >>= 1) v += __shfl_down(v, o, 64);
    if (lane == 0) outFinal[seg] = v + fb2[0];
  }
}

// ---------------------------------------------------------------------------
extern "C" void kernel_launch(void* const* d_in, const int* in_sizes, int n_in,
                              void* d_out, int out_size, void* d_ws, size_t ws_size,
                              hipStream_t stream) {
  const float* interp  = (const float*)d_in[0];
  const float* addInfo = (const float*)d_in[1];
  const int* sizes     = (const int*)d_in[2];
  const int* nbrIdx    = (const int*)d_in[3];
  const int* selfIdx   = (const int*)d_in[4];
  const float* b0W1 = (const float*)d_in[5];
  const float* b0b1 = (const float*)d_in[6];
  const float* b0W2 = (const float*)d_in[7];
  const float* b0b2 = (const float*)d_in[8];
  const float* b0Wo = (const float*)d_in[9];
  const float* b0bo = (const float*)d_in[10];
  const float* b1W1 = (const float*)d_in[11];
  const float* b1b1 = (const float*)d_in[12];
  const float* b1W2 = (const float*)d_in[13];
  const float* b1b2 = (const float*)d_in[14];
  const float* b1Wo = (const float*)d_in[15];
  const float* b1bo = (const float*)d_in[16];
  const float* fW1  = (const float*)d_in[17];
  const float* fb1  = (const float*)d_in[18];
  const float* fW2  = (const float*)d_in[19];
  const float* fb2  = (const float*)d_in[20];

  const int E = in_sizes[1];
  const int ntiles = (E + 15) >> 4;

  char* ws = (char*)d_ws;
  int*            offs = (int*)(ws + 0);                   //  65536
  short*          PB1  = (short*)(ws + 65536);             //  81920
  short*          PB2  = (short*)(ws + 147456);            //  65536
  unsigned short* TAB  = (unsigned short*)(ws + 212992);   //  N*160*2
  float*          HM   = (float*)(ws + 5292032);           //  N*128*4
  unsigned short* H1   = (unsigned short*)(ws + 13418496); //  ntiles*16*128*2
  float*          RES  = (float*)(ws + 78430208);          //  N*129*4

  scan_kernel<<<1, 256, 0, stream>>>(sizes, offs, NSEG);
  wprep_kernel<<<288, 256, 0, stream>>>(b0W1, b1W1, b0W2, b1W2, PB1, PB2);
  prep_kernel<<<NSEG, 128, 0, stream>>>(interp, b0W1, b0b1, TAB, HM);

  // ---- block 0 ----
  gemm1_kernel<<<1024, 256, 0, stream>>>(TAB, PB1, b0W1, HM, addInfo, nbrIdx,
                                         selfIdx, H1, ntiles, E);
  fused2_kernel<0><<<NSEG / 4, 256, 0, stream>>>(
      H1, offs, PB2, b0b2, b0Wo, b0bo, interp, RES, TAB, b1W1, b1b1, HM,
      nullptr, nullptr, nullptr, nullptr, nullptr);

  // ---- block 1 ----
  gemm1_kernel<<<1024, 256, 0, stream>>>(TAB, PB1 + 20480, b1W1, HM, addInfo,
                                         nbrIdx, selfIdx, H1, ntiles, E);
  fused2_kernel<1><<<NSEG / 4, 256, 0, stream>>>(
      H1, offs, PB2 + 16384, b1b2, b1Wo, b1bo, RES, nullptr, nullptr, nullptr,
      nullptr, nullptr, fW1, fb1, fW2, fb2, (float*)d_out);
}

// Round 4
// 329.367 us; speedup vs baseline: 3.2275x; 1.6838x over previous
//
#include <hip/hip_runtime.h>

#define NSEG 15872
#define DD 129
#define HH 128
#define NTILE (NSEG / 16)  // 992 node tiles

typedef __attribute__((ext_vector_type(8))) short s16x8;
typedef __attribute__((ext_vector_type(4))) float f32x4;

__device__ __forceinline__ unsigned short f2bf(float x) {
  union { float f; unsigned u; } c; c.f = x;
  unsigned r = c.u + 0x7FFFu + ((c.u >> 16) & 1u);
  return (unsigned short)(r >> 16);
}

// ---------------------------------------------------------------------------
// offs[N+1] = exclusive scan of sizes
// ---------------------------------------------------------------------------
__global__ __launch_bounds__(256) void scan_kernel(const int* __restrict__ sizes,
                                                   int* __restrict__ offs, int n) {
  __shared__ int sums[256];
  __shared__ int pref[256];
  const int t = threadIdx.x;
  const int chunk = (n + 255) >> 8;
  const int s0 = t * chunk, s1 = min(s0 + chunk, n);
  int s = 0;
  for (int i = s0; i < s1; ++i) s += sizes[i];
  sums[t] = s;
  __syncthreads();
  if (t == 0) { int a = 0; for (int i = 0; i < 256; ++i) { pref[i] = a; a += sums[i]; } }
  __syncthreads();
  int a = pref[t];
  for (int i = s0; i < s1; ++i) { offs[i] = a; a += sizes[i]; }
  if (t == 255) offs[n] = a;
}

// ---------------------------------------------------------------------------
// Generic MFMA B-fragment packer: out[((ks*4+lk)*N + n)*8 + i] =
//   bf16(W[(rowBase + ks*32+lk*8+i)*ld + n])  (0 outside kLimit/ncols)
// ---------------------------------------------------------------------------
__device__ __forceinline__ void packB(short* out, int idx, const float* W,
                                      int N, int ld, int ncols, int kLimit,
                                      int rowBase) {
  const int i = idx & 7;
  const int n = (idx >> 3) % N;
  const int g = idx / (8 * N);
  const int row = g * 8 + i;
  float v = 0.f;
  if (row < kLimit && n < ncols) v = W[(long)(rowBase + row) * ld + n];
  out[idx] = (short)f2bf(v);
}

// PB1 2x20480 | PB2 2x16384 | PWo 2x18432 | PW1m 2x20480 | PfW1 10240
__global__ __launch_bounds__(256) void wprep_kernel(
    const float* __restrict__ W1b0, const float* __restrict__ W1b1,
    const float* __restrict__ W2b0, const float* __restrict__ W2b1,
    const float* __restrict__ Wob0, const float* __restrict__ Wob1,
    const float* __restrict__ fW1, short* __restrict__ PB1,
    short* __restrict__ PB2, short* __restrict__ PWo,
    short* __restrict__ PW1m, short* __restrict__ PfW1) {
  int id = blockIdx.x * 256 + threadIdx.x;
  if (id < 40960) {  // W1 neighbor half, K 129->160, N 128
    packB(PB1 + (id / 20480) * 20480, id % 20480, (id < 20480) ? W1b0 : W1b1,
          128, 128, 128, 129, 0);
    return;
  }
  id -= 40960;
  if (id < 32768) {  // W2, K 128, N 128
    packB(PB2 + (id / 16384) * 16384, id % 16384, (id < 16384) ? W2b0 : W2b1,
          128, 128, 128, 128, 0);
    return;
  }
  id -= 32768;
  if (id < 36864) {  // Wo, K 128, N 129->144
    packB(PWo + (id / 18432) * 18432, id % 18432, (id < 18432) ? Wob0 : Wob1,
          144, 129, 129, 128, 0);
    return;
  }
  id -= 36864;
  if (id < 40960) {  // W1 main half (rows 129..257), K 129->160, N 128
    packB(PW1m + (id / 20480) * 20480, id % 20480, (id < 20480) ? W1b0 : W1b1,
          128, 128, 128, 129, 129);
    return;
  }
  id -= 40960;
  if (id < 10240) packB(PfW1, id, fW1, 64, 64, 64, 129, 0);  // fW1 K 129->160, N 64
}

// ---------------------------------------------------------------------------
// TAB: bf16 node table, stride 160, zero-padded cols 129..159
// ---------------------------------------------------------------------------
__global__ __launch_bounds__(256) void tabprep_kernel(
    const float* __restrict__ interp, unsigned short* __restrict__ tab) {
  const int id = blockIdx.x * 256 + threadIdx.x;  // NSEG*160 exact
  const int n = id / 160, k = id - n * 160;
  tab[id] = (k < DD) ? f2bf(interp[(long)n * DD + k]) : (unsigned short)0;
}

// ---------------------------------------------------------------------------
// HM = b1 + tab @ W1main  (dense MFMA over 16-node tiles)
// ---------------------------------------------------------------------------
__global__ __launch_bounds__(256) void hmprep_kernel(
    const unsigned short* __restrict__ tab, const short* __restrict__ PW1m,
    const float* __restrict__ b1, float* __restrict__ Hm) {
  const int lane = threadIdx.x & 63, w = threadIdx.x >> 6;
  const int lk = lane >> 4, n16 = lane & 15;
  s16x8 B[5][8];
  float bv[8];
#pragma unroll
  for (int ks = 0; ks < 5; ++ks)
#pragma unroll
    for (int nf = 0; nf < 8; ++nf)
      B[ks][nf] = *(const s16x8*)(PW1m + (((ks * 4 + lk) * 128) + nf * 16 + n16) * 8);
#pragma unroll
  for (int nf = 0; nf < 8; ++nf) bv[nf] = b1[nf * 16 + n16];

  const int tile = blockIdx.x * 4 + w;
  const unsigned short* arow = tab + (long)(tile * 16 + n16) * 160;
  s16x8 A[5];
#pragma unroll
  for (int ks = 0; ks < 5; ++ks) A[ks] = *(const s16x8*)(arow + ks * 32 + lk * 8);
  f32x4 C[8];
#pragma unroll
  for (int nf = 0; nf < 8; ++nf) C[nf] = (f32x4){0.f, 0.f, 0.f, 0.f};
#pragma unroll
  for (int ks = 0; ks < 5; ++ks)
#pragma unroll
    for (int nf = 0; nf < 8; ++nf)
      C[nf] = __builtin_amdgcn_mfma_f32_16x16x32_bf16(A[ks], B[ks][nf], C[nf], 0, 0, 0);
#pragma unroll
  for (int nf = 0; nf < 8; ++nf)
#pragma unroll
    for (int r = 0; r < 4; ++r)
      Hm[(long)(tile * 16 + lk * 4 + r) * HH + nf * 16 + n16] = C[nf][r] + bv[nf];
}

// ---------------------------------------------------------------------------
// GEMM1: H1 = relu(gather(tab,nbr) @ W1n + iou*wiou + Hm[self]) with
// next-tile A/iou prefetch overlapping the LDS-bounce epilogue.
// ---------------------------------------------------------------------------
__device__ __forceinline__ void loadA5(s16x8* A, const unsigned short* tab,
                                       const int* nbrIdx, int tile, int E,
                                       int lk, int n16) {
  int er = tile * 16 + n16;
  if (er >= E) er = E - 1;
  const unsigned short* arow = tab + (long)nbrIdx[er] * 160;
#pragma unroll
  for (int ks = 0; ks < 5; ++ks) A[ks] = *(const s16x8*)(arow + ks * 32 + lk * 8);
}
__device__ __forceinline__ void loadIO(float* io, const float* iou, int tile,
                                       int E, int lk) {
  const int e0 = tile << 4;
  if (e0 + 16 <= E) {
    const f32x4 i4 = *(const f32x4*)(iou + e0 + lk * 4);
    io[0] = i4[0]; io[1] = i4[1]; io[2] = i4[2]; io[3] = i4[3];
  } else {
#pragma unroll
    for (int r = 0; r < 4; ++r) {
      int e = e0 + lk * 4 + r;
      io[r] = iou[e < E ? e : (E - 1)];
    }
  }
}

__global__ __launch_bounds__(256) void gemm1_kernel(
    const unsigned short* __restrict__ tab, const short* __restrict__ PB1,
    const float* __restrict__ W1, const float* __restrict__ Hm,
    const float* __restrict__ iou, const int* __restrict__ nbrIdx,
    const int* __restrict__ selfIdx, unsigned short* __restrict__ H1,
    int ntiles, int E) {
  __shared__ __align__(16) float scratch[4][16 * 132];
  const int lane = threadIdx.x & 63;
  const int wslot = threadIdx.x >> 6;
  const int lk = lane >> 4;
  const int n16 = lane & 15;
  float* sc = scratch[wslot];

  s16x8 B[5][8];
  float wv[8];
#pragma unroll
  for (int ks = 0; ks < 5; ++ks)
#pragma unroll
    for (int nf = 0; nf < 8; ++nf)
      B[ks][nf] = *(const s16x8*)(PB1 + (((ks * 4 + lk) * 128) + nf * 16 + n16) * 8);
#pragma unroll
  for (int nf = 0; nf < 8; ++nf) wv[nf] = W1[258 * HH + nf * 16 + n16];

  const int wid = (blockIdx.x << 2) + wslot;
  const int nw = gridDim.x << 2;

  int tile = wid;
  s16x8 A[5];
  float io[4];
  if (tile < ntiles) {
    loadA5(A, tab, nbrIdx, tile, E, lk, n16);
    loadIO(io, iou, tile, E, lk);
  }
  while (tile < ntiles) {
    const int nxt = tile + nw;
    const int e0 = tile << 4;
    f32x4 C[8];
#pragma unroll
    for (int nf = 0; nf < 8; ++nf) C[nf] = (f32x4){0.f, 0.f, 0.f, 0.f};
#pragma unroll
    for (int ks = 0; ks < 5; ++ks)
#pragma unroll
      for (int nf = 0; nf < 8; ++nf)
        C[nf] = __builtin_amdgcn_mfma_f32_16x16x32_bf16(A[ks], B[ks][nf], C[nf], 0, 0, 0);
    // C/D layout -> row-major LDS (stride 132), consuming io
#pragma unroll
    for (int nf = 0; nf < 8; ++nf)
#pragma unroll
      for (int r = 0; r < 4; ++r)
        sc[(lk * 4 + r) * 132 + nf * 16 + n16] = C[nf][r] + io[r] * wv[nf];
    // prefetch next tile's A/iou (A regs free after MFMA, io consumed above)
    if (nxt < ntiles) {
      loadA5(A, tab, nbrIdx, nxt, E, lk, n16);
      loadIO(io, iou, nxt, E, lk);
    }
    // epilogue: row-major readback + Hm[self] + relu + bf16 store
#pragma unroll
    for (int s = 0; s < 4; ++s) {
      const int row = lk + (s << 2);
      const int e = e0 + row;
      const int seg = selfIdx[e < E ? e : (E - 1)];
      const float* hrow = Hm + (long)seg * HH + n16 * 8;
      const f32x4 h0 = *(const f32x4*)(sc + row * 132 + n16 * 8);
      const f32x4 h1 = *(const f32x4*)(sc + row * 132 + n16 * 8 + 4);
      const f32x4 m0 = *(const f32x4*)(hrow);
      const f32x4 m1 = *(const f32x4*)(hrow + 4);
      s16x8 o;
      o[0] = (short)f2bf(fmaxf(h0[0] + m0[0], 0.f));
      o[1] = (short)f2bf(fmaxf(h0[1] + m0[1], 0.f));
      o[2] = (short)f2bf(fmaxf(h0[2] + m0[2], 0.f));
      o[3] = (short)f2bf(fmaxf(h0[3] + m0[3], 0.f));
      o[4] = (short)f2bf(fmaxf(h1[0] + m1[0], 0.f));
      o[5] = (short)f2bf(fmaxf(h1[1] + m1[1], 0.f));
      o[6] = (short)f2bf(fmaxf(h1[2] + m1[2], 0.f));
      o[7] = (short)f2bf(fmaxf(h1[3] + m1[3], 0.f));
      *(s16x8*)(H1 + (long)(e0 + row) * HH + n16 * 8) = o;
    }
    tile = nxt;
  }
}

// ---------------------------------------------------------------------------
// pool: GEMM2 + segment max only. One wave per segment, grid-stride.
// pooled = relu-max, bf16, row-major N x 128.
// ---------------------------------------------------------------------------
__global__ __launch_bounds__(256) void pool_kernel(
    const unsigned short* __restrict__ H1, const int* __restrict__ offs,
    const short* __restrict__ PB2, const float* __restrict__ b2,
    unsigned short* __restrict__ pooled) {
  const int lane = threadIdx.x & 63;
  const int lk = lane >> 4, n16 = lane & 15;
  s16x8 B[4][8];
  float bv[8];
#pragma unroll
  for (int ks = 0; ks < 4; ++ks)
#pragma unroll
    for (int nf = 0; nf < 8; ++nf)
      B[ks][nf] = *(const s16x8*)(PB2 + (((ks * 4 + lk) * 128) + nf * 16 + n16) * 8);
#pragma unroll
  for (int nf = 0; nf < 8; ++nf) bv[nf] = b2[nf * 16 + n16];

  const int wid = (blockIdx.x << 2) + (threadIdx.x >> 6);
  const int nw = gridDim.x << 2;
  for (int seg = wid; seg < NSEG; seg += nw) {
    const int e0 = offs[seg], e1 = offs[seg + 1];
    float pm[8];
#pragma unroll
    for (int nf = 0; nf < 8; ++nf) pm[nf] = 0.f;
    for (int eb = e0; eb < e1; eb += 16) {
      int e = eb + n16;
      if (e >= e1) e = e1 - 1;
      const unsigned short* hrow = H1 + (long)e * HH;
      s16x8 A[4];
#pragma unroll
      for (int ks = 0; ks < 4; ++ks) A[ks] = *(const s16x8*)(hrow + ks * 32 + lk * 8);
      f32x4 C[8];
#pragma unroll
      for (int nf = 0; nf < 8; ++nf) C[nf] = (f32x4){0.f, 0.f, 0.f, 0.f};
#pragma unroll
      for (int ks = 0; ks < 4; ++ks)
#pragma unroll
        for (int nf = 0; nf < 8; ++nf)
          C[nf] = __builtin_amdgcn_mfma_f32_16x16x32_bf16(A[ks], B[ks][nf], C[nf], 0, 0, 0);
#pragma unroll
      for (int nf = 0; nf < 8; ++nf)
#pragma unroll
        for (int r = 0; r < 4; ++r) pm[nf] = fmaxf(pm[nf], C[nf][r] + bv[nf]);
    }
#pragma unroll
    for (int nf = 0; nf < 8; ++nf) {
      float p = pm[nf];
      p = fmaxf(p, __shfl_xor(p, 16, 64));
      p = fmaxf(p, __shfl_xor(p, 32, 64));
      pm[nf] = p;
    }
    if (lane < 16) {
#pragma unroll
      for (int nf = 0; nf < 8; ++nf)
        pooled[(long)seg * HH + nf * 16 + n16] = f2bf(pm[nf]);
    }
  }
}

// ---------------------------------------------------------------------------
// resout: RES = resIn + bo + pooled @ Wo  (MFMA, Wo packed N=144 incl col 128)
// writes RES fp32 (optional) + TAB bf16 (pad cols stay zero from tabprep).
// ---------------------------------------------------------------------------
__global__ __launch_bounds__(256) void resout_kernel(
    const unsigned short* __restrict__ pooled, const short* __restrict__ PWo,
    const float* __restrict__ bo, const float* __restrict__ resIn,
    float* __restrict__ resOut, unsigned short* __restrict__ tab) {
  const int lane = threadIdx.x & 63, w = threadIdx.x >> 6;
  const int lk = lane >> 4, n16 = lane & 15;
  s16x8 B[4][9];
#pragma unroll
  for (int ks = 0; ks < 4; ++ks)
#pragma unroll
    for (int nf = 0; nf < 9; ++nf)
      B[ks][nf] = *(const s16x8*)(PWo + (((ks * 4 + lk) * 144) + nf * 16 + n16) * 8);

  const int tile = blockIdx.x * 4 + w;
  const unsigned short* arow = pooled + (long)(tile * 16 + n16) * HH;
  s16x8 A[4];
#pragma unroll
  for (int ks = 0; ks < 4; ++ks) A[ks] = *(const s16x8*)(arow + ks * 32 + lk * 8);
  f32x4 C[9];
#pragma unroll
  for (int nf = 0; nf < 9; ++nf) C[nf] = (f32x4){0.f, 0.f, 0.f, 0.f};
#pragma unroll
  for (int ks = 0; ks < 4; ++ks)
#pragma unroll
    for (int nf = 0; nf < 9; ++nf)
      C[nf] = __builtin_amdgcn_mfma_f32_16x16x32_bf16(A[ks], B[ks][nf], C[nf], 0, 0, 0);

#pragma unroll
  for (int nf = 0; nf < 8; ++nf)
#pragma unroll
    for (int r = 0; r < 4; ++r) {
      const int col = nf * 16 + n16;
      const long node = tile * 16 + lk * 4 + r;
      const float res = resIn[node * DD + col] + bo[col] + C[nf][r];
      if (resOut) resOut[node * DD + col] = res;
      tab[node * 160 + col] = f2bf(res);
    }
  if (n16 == 0) {
#pragma unroll
    for (int r = 0; r < 4; ++r) {
      const long node = tile * 16 + lk * 4 + r;
      const float res = resIn[node * DD + 128] + bo[128] + C[8][r];
      if (resOut) resOut[node * DD + 128] = res;
      tab[node * 160 + 128] = f2bf(res);
    }
  }
}

// ---------------------------------------------------------------------------
// head: out = relu(tab @ fW1 + fb1) @ fW2 + fb2   (MFMA + shfl reduce)
// ---------------------------------------------------------------------------
__global__ __launch_bounds__(256) void head_kernel(
    const unsigned short* __restrict__ tab, const short* __restrict__ PfW1,
    const float* __restrict__ fb1, const float* __restrict__ fW2,
    const float* __restrict__ fb2, float* __restrict__ out) {
  const int lane = threadIdx.x & 63, w = threadIdx.x >> 6;
  const int lk = lane >> 4, n16 = lane & 15;
  s16x8 B[5][4];
  float b1v[4], w2v[4];
#pragma unroll
  for (int ks = 0; ks < 5; ++ks)
#pragma unroll
    for (int nf = 0; nf < 4; ++nf)
      B[ks][nf] = *(const s16x8*)(PfW1 + (((ks * 4 + lk) * 64) + nf * 16 + n16) * 8);
#pragma unroll
  for (int nf = 0; nf < 4; ++nf) {
    b1v[nf] = fb1[nf * 16 + n16];
    w2v[nf] = fW2[nf * 16 + n16];
  }
  const int tile = blockIdx.x * 4 + w;
  const unsigned short* arow = tab + (long)(tile * 16 + n16) * 160;
  s16x8 A[5];
#pragma unroll
  for (int ks = 0; ks < 5; ++ks) A[ks] = *(const s16x8*)(arow + ks * 32 + lk * 8);
  f32x4 C[4];
#pragma unroll
  for (int nf = 0; nf < 4; ++nf) C[nf] = (f32x4){0.f, 0.f, 0.f, 0.f};
#pragma unroll
  for (int ks = 0; ks < 5; ++ks)
#pragma unroll
    for (int nf = 0; nf < 4; ++nf)
      C[nf] = __builtin_amdgcn_mfma_f32_16x16x32_bf16(A[ks], B[ks][nf], C[nf], 0, 0, 0);
#pragma unroll
  for (int r = 0; r < 4; ++r) {
    float s = 0.f;
#pragma unroll
    for (int nf = 0; nf < 4; ++nf)
      s += fmaxf(C[nf][r] + b1v[nf], 0.f) * w2v[nf];
    s += __shfl_xor(s, 1, 64);
    s += __shfl_xor(s, 2, 64);
    s += __shfl_xor(s, 4, 64);
    s += __shfl_xor(s, 8, 64);
    if (n16 == 0) out[tile * 16 + lk * 4 + r] = s + fb2[0];
  }
}

// ---------------------------------------------------------------------------
extern "C" void kernel_launch(void* const* d_in, const int* in_sizes, int n_in,
                              void* d_out, int out_size, void* d_ws, size_t ws_size,
                              hipStream_t stream) {
  const float* interp  = (const float*)d_in[0];
  const float* addInfo = (const float*)d_in[1];
  const int* sizes     = (const int*)d_in[2];
  const int* nbrIdx    = (const int*)d_in[3];
  const int* selfIdx   = (const int*)d_in[4];
  const float* b0W1 = (const float*)d_in[5];
  const float* b0b1 = (const float*)d_in[6];
  const float* b0W2 = (const float*)d_in[7];
  const float* b0b2 = (const float*)d_in[8];
  const float* b0Wo = (const float*)d_in[9];
  const float* b0bo = (const float*)d_in[10];
  const float* b1W1 = (const float*)d_in[11];
  const float* b1b1 = (const float*)d_in[12];
  const float* b1W2 = (const float*)d_in[13];
  const float* b1b2 = (const float*)d_in[14];
  const float* b1Wo = (const float*)d_in[15];
  const float* b1bo = (const float*)d_in[16];
  const float* fW1  = (const float*)d_in[17];
  const float* fb1  = (const float*)d_in[18];
  const float* fW2  = (const float*)d_in[19];
  const float* fb2  = (const float*)d_in[20];

  const int E = in_sizes[1];
  const int ntiles = (E + 15) >> 4;

  char* ws = (char*)d_ws;
  int*            offs  = (int*)(ws + 0);                    // 65536
  short*          PB1   = (short*)(ws + 65536);              // 81920
  short*          PB2   = (short*)(ws + 147456);             // 65536
  short*          PWo   = (short*)(ws + 212992);             // 73728
  short*          PW1m  = (short*)(ws + 286720);             // 81920
  short*          PfW1  = (short*)(ws + 368640);             // 20480 -> pad
  unsigned short* TAB   = (unsigned short*)(ws + 393216);    // N*160*2
  float*          HM    = (float*)(ws + 5472256);            // N*128*4
  unsigned short* POOLED= (unsigned short*)(ws + 13598720);  // N*128*2
  float*          RES   = (float*)(ws + 17661952);           // N*129*4
  unsigned short* H1    = (unsigned short*)(ws + 25851904);  // ntiles*16*128*2

  scan_kernel<<<1, 256, 0, stream>>>(sizes, offs, NSEG);
  wprep_kernel<<<632, 256, 0, stream>>>(b0W1, b1W1, b0W2, b1W2, b0Wo, b1Wo,
                                        fW1, PB1, PB2, PWo, PW1m, PfW1);
  tabprep_kernel<<<NSEG * 160 / 256, 256, 0, stream>>>(interp, TAB);

  // ---- block 0 ----
  hmprep_kernel<<<NTILE / 4, 256, 0, stream>>>(TAB, PW1m, b0b1, HM);
  gemm1_kernel<<<1024, 256, 0, stream>>>(TAB, PB1, b0W1, HM, addInfo, nbrIdx,
                                         selfIdx, H1, ntiles, E);
  pool_kernel<<<992, 256, 0, stream>>>(H1, offs, PB2, b0b2, POOLED);
  resout_kernel<<<NTILE / 4, 256, 0, stream>>>(POOLED, PWo, b0bo, interp, RES, TAB);

  // ---- block 1 ----
  hmprep_kernel<<<NTILE / 4, 256, 0, stream>>>(TAB, PW1m + 20480, b1b1, HM);
  gemm1_kernel<<<1024, 256, 0, stream>>>(TAB, PB1 + 20480, b1W1, HM, addInfo,
                                         nbrIdx, selfIdx, H1, ntiles, E);
  pool_kernel<<<992, 256, 0, stream>>>(H1, offs, PB2 + 16384, b1b2, POOLED);
  resout_kernel<<<NTILE / 4, 256, 0, stream>>>(POOLED, PWo + 18432, b1bo, RES,
                                               nullptr, TAB);

  head_kernel<<<NTILE / 4, 256, 0, stream>>>(TAB, PfW1, fb1, fW2, fb2,
                                             (float*)d_out);
}

// Round 5
// 285.574 us; speedup vs baseline: 3.7224x; 1.1534x over previous
//
#include <hip/hip_runtime.h>

#define NSEG 15872
#define DD 129
#define HH 128
#define NTILE (NSEG / 16)  // 992 node tiles

typedef __attribute__((ext_vector_type(8))) short s16x8;
typedef __attribute__((ext_vector_type(4))) float f32x4;

__device__ __forceinline__ unsigned short f2bf(float x) {
  union { float f; unsigned u; } c; c.f = x;
  unsigned r = c.u + 0x7FFFu + ((c.u >> 16) & 1u);
  return (unsigned short)(r >> 16);
}

// ---------------------------------------------------------------------------
// Generic MFMA B-fragment packer: out[((g)*N + n)*8 + i] =
//   bf16(W[(rowBase + g*8+i)*ld + n])  (0 outside kLimit/ncols)
// ---------------------------------------------------------------------------
__device__ __forceinline__ void packB(short* out, int idx, const float* W,
                                      int N, int ld, int ncols, int kLimit,
                                      int rowBase) {
  const int i = idx & 7;
  const int n = (idx >> 3) % N;
  const int g = idx / (8 * N);
  const int row = g * 8 + i;
  float v = 0.f;
  if (row < kLimit && n < ncols) v = W[(long)(rowBase + row) * ld + n];
  out[idx] = (short)f2bf(v);
}

// ---------------------------------------------------------------------------
// prep_all: block 0 = exclusive scan of sizes; blocks 1..632 = weight packing;
// blocks 633.. = bf16 node table (stride 160, zero pad).
// ---------------------------------------------------------------------------
#define PACK_IDS 161792  // 40960+32768+36864+40960+10240
#define TAB_IDS (NSEG * 160)
__global__ __launch_bounds__(256) void prep_all_kernel(
    const int* __restrict__ sizes, int* __restrict__ offs,
    const float* __restrict__ interp, unsigned short* __restrict__ tab,
    const float* __restrict__ W1b0, const float* __restrict__ W1b1,
    const float* __restrict__ W2b0, const float* __restrict__ W2b1,
    const float* __restrict__ Wob0, const float* __restrict__ Wob1,
    const float* __restrict__ fW1, short* __restrict__ PB1,
    short* __restrict__ PB2, short* __restrict__ PWo,
    short* __restrict__ PW1m, short* __restrict__ PfW1) {
  if (blockIdx.x == 0) {
    __shared__ int sums[256];
    __shared__ int pref[256];
    const int t = threadIdx.x;
    const int chunk = (NSEG + 255) >> 8;
    const int s0 = t * chunk, s1 = min(s0 + chunk, NSEG);
    int s = 0;
    for (int i = s0; i < s1; ++i) s += sizes[i];
    sums[t] = s;
    __syncthreads();
    if (t == 0) { int a = 0; for (int i = 0; i < 256; ++i) { pref[i] = a; a += sums[i]; } }
    __syncthreads();
    int a = pref[t];
    for (int i = s0; i < s1; ++i) { offs[i] = a; a += sizes[i]; }
    if (t == 255) offs[NSEG] = a;
    return;
  }
  int id = (blockIdx.x - 1) * 256 + threadIdx.x;
  if (id < PACK_IDS) {
    if (id < 40960) {  // W1 neighbor half, K 129->160, N 128
      packB(PB1 + (id / 20480) * 20480, id % 20480, (id < 20480) ? W1b0 : W1b1,
            128, 128, 128, 129, 0);
      return;
    }
    id -= 40960;
    if (id < 32768) {  // W2, K 128, N 128
      packB(PB2 + (id / 16384) * 16384, id % 16384, (id < 16384) ? W2b0 : W2b1,
            128, 128, 128, 128, 0);
      return;
    }
    id -= 32768;
    if (id < 36864) {  // Wo, K 128, N 129->144
      packB(PWo + (id / 18432) * 18432, id % 18432, (id < 18432) ? Wob0 : Wob1,
            144, 129, 129, 128, 0);
      return;
    }
    id -= 36864;
    if (id < 40960) {  // W1 main half (rows 129..257), K 129->160, N 128
      packB(PW1m + (id / 20480) * 20480, id % 20480, (id < 20480) ? W1b0 : W1b1,
            128, 128, 128, 129, 129);
      return;
    }
    id -= 40960;
    packB(PfW1, id, fW1, 64, 64, 64, 129, 0);  // fW1 K 129->160, N 64
    return;
  }
  id -= PACK_IDS;
  if (id < TAB_IDS) {
    const int n = id / 160, k = id - n * 160;
    tab[id] = (k < DD) ? f2bf(interp[(long)n * DD + k]) : (unsigned short)0;
  }
}

// ---------------------------------------------------------------------------
// HM = b1 + tab @ W1main  (dense MFMA over 16-node tiles)
// ---------------------------------------------------------------------------
__global__ __launch_bounds__(256) void hmprep_kernel(
    const unsigned short* __restrict__ tab, const short* __restrict__ PW1m,
    const float* __restrict__ b1, float* __restrict__ Hm) {
  const int lane = threadIdx.x & 63, w = threadIdx.x >> 6;
  const int lk = lane >> 4, n16 = lane & 15;
  s16x8 B[5][8];
  float bv[8];
#pragma unroll
  for (int ks = 0; ks < 5; ++ks)
#pragma unroll
    for (int nf = 0; nf < 8; ++nf)
      B[ks][nf] = *(const s16x8*)(PW1m + (((ks * 4 + lk) * 128) + nf * 16 + n16) * 8);
#pragma unroll
  for (int nf = 0; nf < 8; ++nf) bv[nf] = b1[nf * 16 + n16];

  const int tile = blockIdx.x * 4 + w;
  const unsigned short* arow = tab + (long)(tile * 16 + n16) * 160;
  s16x8 A[5];
#pragma unroll
  for (int ks = 0; ks < 5; ++ks) A[ks] = *(const s16x8*)(arow + ks * 32 + lk * 8);
  f32x4 C[8];
#pragma unroll
  for (int nf = 0; nf < 8; ++nf) C[nf] = (f32x4){0.f, 0.f, 0.f, 0.f};
#pragma unroll
  for (int ks = 0; ks < 5; ++ks)
#pragma unroll
    for (int nf = 0; nf < 8; ++nf)
      C[nf] = __builtin_amdgcn_mfma_f32_16x16x32_bf16(A[ks], B[ks][nf], C[nf], 0, 0, 0);
#pragma unroll
  for (int nf = 0; nf < 8; ++nf)
#pragma unroll
    for (int r = 0; r < 4; ++r)
      Hm[(long)(tile * 16 + lk * 4 + r) * HH + nf * 16 + n16] = C[nf][r] + bv[nf];
}

// ---------------------------------------------------------------------------
// GEMM1: H1 = relu(gather(tab,nbr) @ W1n + iou*wiou + Hm[self]).
// B (packed W1n) staged in LDS once per block; ds_read_b128 just-in-time.
// Next-tile A/iou prefetch overlaps the LDS-bounce epilogue.
// ---------------------------------------------------------------------------
__device__ __forceinline__ void loadA5(s16x8* A, const unsigned short* tab,
                                       const int* nbrIdx, int tile, int E,
                                       int lk, int n16) {
  int er = tile * 16 + n16;
  if (er >= E) er = E - 1;
  const unsigned short* arow = tab + (long)nbrIdx[er] * 160;
#pragma unroll
  for (int ks = 0; ks < 5; ++ks) A[ks] = *(const s16x8*)(arow + ks * 32 + lk * 8);
}
__device__ __forceinline__ void loadIO(float* io, const float* iou, int tile,
                                       int E, int lk) {
  const int e0 = tile << 4;
  if (e0 + 16 <= E) {
    const f32x4 i4 = *(const f32x4*)(iou + e0 + lk * 4);
    io[0] = i4[0]; io[1] = i4[1]; io[2] = i4[2]; io[3] = i4[3];
  } else {
#pragma unroll
    for (int r = 0; r < 4; ++r) {
      int e = e0 + lk * 4 + r;
      io[r] = iou[e < E ? e : (E - 1)];
    }
  }
}

__global__ __launch_bounds__(256) void gemm1_kernel(
    const unsigned short* __restrict__ tab, const short* __restrict__ PB1,
    const float* __restrict__ W1, const float* __restrict__ Hm,
    const float* __restrict__ iou, const int* __restrict__ nbrIdx,
    const int* __restrict__ selfIdx, unsigned short* __restrict__ H1,
    int ntiles, int E) {
  extern __shared__ __align__(16) char smem[];
  short* Bs = (short*)smem;                        // 40960 B
  float* scratch = (float*)(smem + 40960);         // 4 * 16*132 * 4 B
  {  // stage packed B into LDS (2560 float4)
    const f32x4* src = (const f32x4*)PB1;
    f32x4* dst = (f32x4*)Bs;
    for (int i = threadIdx.x; i < 2560; i += 256) dst[i] = src[i];
  }
  __syncthreads();

  const int lane = threadIdx.x & 63;
  const int wslot = threadIdx.x >> 6;
  const int lk = lane >> 4;
  const int n16 = lane & 15;
  float* sc = scratch + wslot * (16 * 132);

  float wv[8];
#pragma unroll
  for (int nf = 0; nf < 8; ++nf) wv[nf] = W1[258 * HH + nf * 16 + n16];

  const int wid = (blockIdx.x << 2) + wslot;
  const int nw = gridDim.x << 2;

  int tile = wid;
  s16x8 A[5];
  float io[4];
  if (tile < ntiles) {
    loadA5(A, tab, nbrIdx, tile, E, lk, n16);
    loadIO(io, iou, tile, E, lk);
  }
  while (tile < ntiles) {
    const int nxt = tile + nw;
    const int e0 = tile << 4;
    f32x4 C[8];
#pragma unroll
    for (int nf = 0; nf < 8; ++nf) C[nf] = (f32x4){0.f, 0.f, 0.f, 0.f};
#pragma unroll
    for (int ks = 0; ks < 5; ++ks)
#pragma unroll
      for (int nf = 0; nf < 8; ++nf) {
        const s16x8 b = *(const s16x8*)(Bs + (((ks * 4 + lk) * 128) + nf * 16 + n16) * 8);
        C[nf] = __builtin_amdgcn_mfma_f32_16x16x32_bf16(A[ks], b, C[nf], 0, 0, 0);
      }
    // C/D layout -> row-major LDS (stride 132), consuming io
#pragma unroll
    for (int nf = 0; nf < 8; ++nf)
#pragma unroll
      for (int r = 0; r < 4; ++r)
        sc[(lk * 4 + r) * 132 + nf * 16 + n16] = C[nf][r] + io[r] * wv[nf];
    // prefetch next tile's A/iou (A regs free after MFMA, io consumed above)
    if (nxt < ntiles) {
      loadA5(A, tab, nbrIdx, nxt, E, lk, n16);
      loadIO(io, iou, nxt, E, lk);
    }
    // epilogue: row-major readback + Hm[self] + relu + bf16 store
#pragma unroll
    for (int s = 0; s < 4; ++s) {
      const int row = lk + (s << 2);
      const int e = e0 + row;
      const int seg = selfIdx[e < E ? e : (E - 1)];
      const float* hrow = Hm + (long)seg * HH + n16 * 8;
      const f32x4 h0 = *(const f32x4*)(sc + row * 132 + n16 * 8);
      const f32x4 h1 = *(const f32x4*)(sc + row * 132 + n16 * 8 + 4);
      const f32x4 m0 = *(const f32x4*)(hrow);
      const f32x4 m1 = *(const f32x4*)(hrow + 4);
      s16x8 o;
      o[0] = (short)f2bf(fmaxf(h0[0] + m0[0], 0.f));
      o[1] = (short)f2bf(fmaxf(h0[1] + m0[1], 0.f));
      o[2] = (short)f2bf(fmaxf(h0[2] + m0[2], 0.f));
      o[3] = (short)f2bf(fmaxf(h0[3] + m0[3], 0.f));
      o[4] = (short)f2bf(fmaxf(h1[0] + m1[0], 0.f));
      o[5] = (short)f2bf(fmaxf(h1[1] + m1[1], 0.f));
      o[6] = (short)f2bf(fmaxf(h1[2] + m1[2], 0.f));
      o[7] = (short)f2bf(fmaxf(h1[3] + m1[3], 0.f));
      *(s16x8*)(H1 + (long)(e0 + row) * HH + n16 * 8) = o;
    }
    tile = nxt;
  }
}

// ---------------------------------------------------------------------------
// pool: GEMM2 + segment max. One wave per segment, grid-stride.
// B (packed W2) staged in LDS once per block.
// ---------------------------------------------------------------------------
__global__ __launch_bounds__(256) void pool_kernel(
    const unsigned short* __restrict__ H1, const int* __restrict__ offs,
    const short* __restrict__ PB2, const float* __restrict__ b2,
    unsigned short* __restrict__ pooled) {
  extern __shared__ __align__(16) char smem2[];
  short* Bs = (short*)smem2;  // 32768 B
  {
    const f32x4* src = (const f32x4*)PB2;
    f32x4* dst = (f32x4*)Bs;
    for (int i = threadIdx.x; i < 2048; i += 256) dst[i] = src[i];
  }
  __syncthreads();

  const int lane = threadIdx.x & 63;
  const int lk = lane >> 4, n16 = lane & 15;
  float bv[8];
#pragma unroll
  for (int nf = 0; nf < 8; ++nf) bv[nf] = b2[nf * 16 + n16];

  const int wid = (blockIdx.x << 2) + (threadIdx.x >> 6);
  const int nw = gridDim.x << 2;
  for (int seg = wid; seg < NSEG; seg += nw) {
    const int e0 = offs[seg], e1 = offs[seg + 1];
    float pm[8];
#pragma unroll
    for (int nf = 0; nf < 8; ++nf) pm[nf] = 0.f;
    for (int eb = e0; eb < e1; eb += 16) {
      int e = eb + n16;
      if (e >= e1) e = e1 - 1;
      const unsigned short* hrow = H1 + (long)e * HH;
      s16x8 A[4];
#pragma unroll
      for (int ks = 0; ks < 4; ++ks) A[ks] = *(const s16x8*)(hrow + ks * 32 + lk * 8);
      f32x4 C[8];
#pragma unroll
      for (int nf = 0; nf < 8; ++nf) C[nf] = (f32x4){0.f, 0.f, 0.f, 0.f};
#pragma unroll
      for (int ks = 0; ks < 4; ++ks)
#pragma unroll
        for (int nf = 0; nf < 8; ++nf) {
          const s16x8 b = *(const s16x8*)(Bs + (((ks * 4 + lk) * 128) + nf * 16 + n16) * 8);
          C[nf] = __builtin_amdgcn_mfma_f32_16x16x32_bf16(A[ks], b, C[nf], 0, 0, 0);
        }
#pragma unroll
      for (int nf = 0; nf < 8; ++nf)
#pragma unroll
        for (int r = 0; r < 4; ++r) pm[nf] = fmaxf(pm[nf], C[nf][r] + bv[nf]);
    }
#pragma unroll
    for (int nf = 0; nf < 8; ++nf) {
      float p = pm[nf];
      p = fmaxf(p, __shfl_xor(p, 16, 64));
      p = fmaxf(p, __shfl_xor(p, 32, 64));
      pm[nf] = p;
    }
    if (lane < 16) {
#pragma unroll
      for (int nf = 0; nf < 8; ++nf)
        pooled[(long)seg * HH + nf * 16 + n16] = f2bf(pm[nf]);
    }
  }
}

// ---------------------------------------------------------------------------
// resout: RES = resIn + bo + pooled @ Wo  (MFMA, Wo packed N=144 incl col 128)
// writes RES fp32 (optional) + TAB bf16 (pad cols stay zero from prep).
// ---------------------------------------------------------------------------
__global__ __launch_bounds__(256) void resout_kernel(
    const unsigned short* __restrict__ pooled, const short* __restrict__ PWo,
    const float* __restrict__ bo, const float* __restrict__ resIn,
    float* __restrict__ resOut, unsigned short* __restrict__ tab) {
  const int lane = threadIdx.x & 63, w = threadIdx.x >> 6;
  const int lk = lane >> 4, n16 = lane & 15;
  s16x8 B[4][9];
#pragma unroll
  for (int ks = 0; ks < 4; ++ks)
#pragma unroll
    for (int nf = 0; nf < 9; ++nf)
      B[ks][nf] = *(const s16x8*)(PWo + (((ks * 4 + lk) * 144) + nf * 16 + n16) * 8);

  const int tile = blockIdx.x * 4 + w;
  const unsigned short* arow = pooled + (long)(tile * 16 + n16) * HH;
  s16x8 A[4];
#pragma unroll
  for (int ks = 0; ks < 4; ++ks) A[ks] = *(const s16x8*)(arow + ks * 32 + lk * 8);
  f32x4 C[9];
#pragma unroll
  for (int nf = 0; nf < 9; ++nf) C[nf] = (f32x4){0.f, 0.f, 0.f, 0.f};
#pragma unroll
  for (int ks = 0; ks < 4; ++ks)
#pragma unroll
    for (int nf = 0; nf < 9; ++nf)
      C[nf] = __builtin_amdgcn_mfma_f32_16x16x32_bf16(A[ks], B[ks][nf], C[nf], 0, 0, 0);

#pragma unroll
  for (int nf = 0; nf < 8; ++nf)
#pragma unroll
    for (int r = 0; r < 4; ++r) {
      const int col = nf * 16 + n16;
      const long node = tile * 16 + lk * 4 + r;
      const float res = resIn[node * DD + col] + bo[col] + C[nf][r];
      if (resOut) resOut[node * DD + col] = res;
      tab[node * 160 + col] = f2bf(res);
    }
  if (n16 == 0) {
#pragma unroll
    for (int r = 0; r < 4; ++r) {
      const long node = tile * 16 + lk * 4 + r;
      const float res = resIn[node * DD + 128] + bo[128] + C[8][r];
      if (resOut) resOut[node * DD + 128] = res;
      tab[node * 160 + 128] = f2bf(res);
    }
  }
}

// ---------------------------------------------------------------------------
// head: out = relu(tab @ fW1 + fb1) @ fW2 + fb2   (MFMA + shfl reduce)
// ---------------------------------------------------------------------------
__global__ __launch_bounds__(256) void head_kernel(
    const unsigned short* __restrict__ tab, const short* __restrict__ PfW1,
    const float* __restrict__ fb1, const float* __restrict__ fW2,
    const float* __restrict__ fb2, float* __restrict__ out) {
  const int lane = threadIdx.x & 63, w = threadIdx.x >> 6;
  const int lk = lane >> 4, n16 = lane & 15;
  s16x8 B[5][4];
  float b1v[4], w2v[4];
#pragma unroll
  for (int ks = 0; ks < 5; ++ks)
#pragma unroll
    for (int nf = 0; nf < 4; ++nf)
      B[ks][nf] = *(const s16x8*)(PfW1 + (((ks * 4 + lk) * 64) + nf * 16 + n16) * 8);
#pragma unroll
  for (int nf = 0; nf < 4; ++nf) {
    b1v[nf] = fb1[nf * 16 + n16];
    w2v[nf] = fW2[nf * 16 + n16];
  }
  const int tile = blockIdx.x * 4 + w;
  const unsigned short* arow = tab + (long)(tile * 16 + n16) * 160;
  s16x8 A[5];
#pragma unroll
  for (int ks = 0; ks < 5; ++ks) A[ks] = *(const s16x8*)(arow + ks * 32 + lk * 8);
  f32x4 C[4];
#pragma unroll
  for (int nf = 0; nf < 4; ++nf) C[nf] = (f32x4){0.f, 0.f, 0.f, 0.f};
#pragma unroll
  for (int ks = 0; ks < 5; ++ks)
#pragma unroll
    for (int nf = 0; nf < 4; ++nf)
      C[nf] = __builtin_amdgcn_mfma_f32_16x16x32_bf16(A[ks], B[ks][nf], C[nf], 0, 0, 0);
#pragma unroll
  for (int r = 0; r < 4; ++r) {
    float s = 0.f;
#pragma unroll
    for (int nf = 0; nf < 4; ++nf)
      s += fmaxf(C[nf][r] + b1v[nf], 0.f) * w2v[nf];
    s += __shfl_xor(s, 1, 64);
    s += __shfl_xor(s, 2, 64);
    s += __shfl_xor(s, 4, 64);
    s += __shfl_xor(s, 8, 64);
    if (n16 == 0) out[tile * 16 + lk * 4 + r] = s + fb2[0];
  }
}

// ---------------------------------------------------------------------------
extern "C" void kernel_launch(void* const* d_in, const int* in_sizes, int n_in,
                              void* d_out, int out_size, void* d_ws, size_t ws_size,
                              hipStream_t stream) {
  const float* interp  = (const float*)d_in[0];
  const float* addInfo = (const float*)d_in[1];
  const int* sizes     = (const int*)d_in[2];
  const int* nbrIdx    = (const int*)d_in[3];
  const int* selfIdx   = (const int*)d_in[4];
  const float* b0W1 = (const float*)d_in[5];
  const float* b0b1 = (const float*)d_in[6];
  const float* b0W2 = (const float*)d_in[7];
  const float* b0b2 = (const float*)d_in[8];
  const float* b0Wo = (const float*)d_in[9];
  const float* b0bo = (const float*)d_in[10];
  const float* b1W1 = (const float*)d_in[11];
  const float* b1b1 = (const float*)d_in[12];
  const float* b1W2 = (const float*)d_in[13];
  const float* b1b2 = (const float*)d_in[14];
  const float* b1Wo = (const float*)d_in[15];
  const float* b1bo = (const float*)d_in[16];
  const float* fW1  = (const float*)d_in[17];
  const float* fb1  = (const float*)d_in[18];
  const float* fW2  = (const float*)d_in[19];
  const float* fb2  = (const float*)d_in[20];

  const int E = in_sizes[1];
  const int ntiles = (E + 15) >> 4;

  char* ws = (char*)d_ws;
  int*            offs  = (int*)(ws + 0);                    // 65536
  short*          PB1   = (short*)(ws + 65536);              // 81920
  short*          PB2   = (short*)(ws + 147456);             // 65536
  short*          PWo   = (short*)(ws + 212992);             // 73728
  short*          PW1m  = (short*)(ws + 286720);             // 81920
  short*          PfW1  = (short*)(ws + 368640);             // 20480 -> pad
  unsigned short* TAB   = (unsigned short*)(ws + 393216);    // N*160*2
  float*          HM    = (float*)(ws + 5472256);            // N*128*4
  unsigned short* POOLED= (unsigned short*)(ws + 13598720);  // N*128*2
  float*          RES   = (float*)(ws + 17661952);           // N*129*4
  unsigned short* H1    = (unsigned short*)(ws + 25851904);  // ntiles*16*128*2

  const int prep_blocks = 1 + (PACK_IDS / 256) + (TAB_IDS / 256);  // 10553
  prep_all_kernel<<<prep_blocks, 256, 0, stream>>>(
      sizes, offs, interp, TAB, b0W1, b1W1, b0W2, b1W2, b0Wo, b1Wo, fW1,
      PB1, PB2, PWo, PW1m, PfW1);

  const size_t g1_lds = 40960 + 4 * 16 * 132 * 4;  // 74752
  const size_t pl_lds = 32768;

  // ---- block 0 ----
  hmprep_kernel<<<NTILE / 4, 256, 0, stream>>>(TAB, PW1m, b0b1, HM);
  gemm1_kernel<<<1024, 256, g1_lds, stream>>>(TAB, PB1, b0W1, HM, addInfo,
                                              nbrIdx, selfIdx, H1, ntiles, E);
  pool_kernel<<<992, 256, pl_lds, stream>>>(H1, offs, PB2, b0b2, POOLED);
  resout_kernel<<<NTILE / 4, 256, 0, stream>>>(POOLED, PWo, b0bo, interp, RES, TAB);

  // ---- block 1 ----
  hmprep_kernel<<<NTILE / 4, 256, 0, stream>>>(TAB, PW1m + 20480, b1b1, HM);
  gemm1_kernel<<<1024, 256, g1_lds, stream>>>(TAB, PB1 + 20480, b1W1, HM,
                                              addInfo, nbrIdx, selfIdx, H1,
                                              ntiles, E);
  pool_kernel<<<992, 256, pl_lds, stream>>>(H1, offs, PB2 + 16384, b1b2, POOLED);
  resout_kernel<<<NTILE / 4, 256, 0, stream>>>(POOLED, PWo + 18432, b1bo, RES,
                                               nullptr, TAB);

  head_kernel<<<NTILE / 4, 256, 0, stream>>>(TAB, PfW1, fb1, fW2, fb2,
                                             (float*)d_out);
}

// Round 6
// 264.116 us; speedup vs baseline: 4.0249x; 1.0812x over previous
//
#include <hip/hip_runtime.h>

#define NSEG 15872
#define DD 129
#define HH 128
#define NTILE (NSEG / 16)  // 992 node tiles

typedef __attribute__((ext_vector_type(8))) short s16x8;
typedef __attribute__((ext_vector_type(4))) float f32x4;

__device__ __forceinline__ unsigned short f2bf(float x) {
  union { float f; unsigned u; } c; c.f = x;
  unsigned r = c.u + 0x7FFFu + ((c.u >> 16) & 1u);
  return (unsigned short)(r >> 16);
}

// ---------------------------------------------------------------------------
// Generic MFMA B-fragment packer: out[(g*N + n)*8 + i] =
//   bf16(W[(rowBase + g*8+i)*ld + n])  (0 outside kLimit/ncols)
// ---------------------------------------------------------------------------
__device__ __forceinline__ void packB(short* out, int idx, const float* W,
                                      int N, int ld, int ncols, int kLimit,
                                      int rowBase) {
  const int i = idx & 7;
  const int n = (idx >> 3) % N;
  const int g = idx / (8 * N);
  const int row = g * 8 + i;
  float v = 0.f;
  if (row < kLimit && n < ncols) v = W[(long)(rowBase + row) * ld + n];
  out[idx] = (short)f2bf(v);
}

// ---------------------------------------------------------------------------
// prep_all: block 0 = scan; blocks 1..632 = weight packing; rest = bf16 TAB.
// ---------------------------------------------------------------------------
#define PACK_IDS 161792  // 40960+32768+36864+40960+10240
#define TAB_IDS (NSEG * 160)
__global__ __launch_bounds__(256) void prep_all_kernel(
    const int* __restrict__ sizes, int* __restrict__ offs,
    const float* __restrict__ interp, unsigned short* __restrict__ tab,
    const float* __restrict__ W1b0, const float* __restrict__ W1b1,
    const float* __restrict__ W2b0, const float* __restrict__ W2b1,
    const float* __restrict__ Wob0, const float* __restrict__ Wob1,
    const float* __restrict__ fW1, short* __restrict__ PB1,
    short* __restrict__ PB2, short* __restrict__ PWo,
    short* __restrict__ PW1m, short* __restrict__ PfW1) {
  if (blockIdx.x == 0) {
    __shared__ int sums[256];
    __shared__ int pref[256];
    const int t = threadIdx.x;
    const int chunk = (NSEG + 255) >> 8;
    const int s0 = t * chunk, s1 = min(s0 + chunk, NSEG);
    int s = 0;
    for (int i = s0; i < s1; ++i) s += sizes[i];
    sums[t] = s;
    __syncthreads();
    if (t == 0) { int a = 0; for (int i = 0; i < 256; ++i) { pref[i] = a; a += sums[i]; } }
    __syncthreads();
    int a = pref[t];
    for (int i = s0; i < s1; ++i) { offs[i] = a; a += sizes[i]; }
    if (t == 255) offs[NSEG] = a;
    return;
  }
  int id = (blockIdx.x - 1) * 256 + threadIdx.x;
  if (id < PACK_IDS) {
    if (id < 40960) {  // W1 neighbor half, K 129->160, N 128
      packB(PB1 + (id / 20480) * 20480, id % 20480, (id < 20480) ? W1b0 : W1b1,
            128, 128, 128, 129, 0);
      return;
    }
    id -= 40960;
    if (id < 32768) {  // W2, K 128, N 128
      packB(PB2 + (id / 16384) * 16384, id % 16384, (id < 16384) ? W2b0 : W2b1,
            128, 128, 128, 128, 0);
      return;
    }
    id -= 32768;
    if (id < 36864) {  // Wo, K 128, N 129->144
      packB(PWo + (id / 18432) * 18432, id % 18432, (id < 18432) ? Wob0 : Wob1,
            144, 129, 129, 128, 0);
      return;
    }
    id -= 36864;
    if (id < 40960) {  // W1 main half (rows 129..257), K 129->160, N 128
      packB(PW1m + (id / 20480) * 20480, id % 20480, (id < 20480) ? W1b0 : W1b1,
            128, 128, 128, 129, 129);
      return;
    }
    id -= 40960;
    packB(PfW1, id, fW1, 64, 64, 64, 129, 0);  // fW1 K 129->160, N 64
    return;
  }
  id -= PACK_IDS;
  if (id < TAB_IDS) {
    const int n = id / 160, k = id - n * 160;
    tab[id] = (k < DD) ? f2bf(interp[(long)n * DD + k]) : (unsigned short)0;
  }
}

// ---------------------------------------------------------------------------
// HM = b1 + tab @ W1main  (dense MFMA over 16-node tiles; block-0 only)
// ---------------------------------------------------------------------------
__global__ __launch_bounds__(256) void hmprep_kernel(
    const unsigned short* __restrict__ tab, const short* __restrict__ PW1m,
    const float* __restrict__ b1, float* __restrict__ Hm) {
  const int lane = threadIdx.x & 63, w = threadIdx.x >> 6;
  const int lk = lane >> 4, n16 = lane & 15;
  const int tile = blockIdx.x * 4 + w;
  const unsigned short* arow = tab + (long)(tile * 16 + n16) * 160;
  s16x8 A[5];
#pragma unroll
  for (int ks = 0; ks < 5; ++ks) A[ks] = *(const s16x8*)(arow + ks * 32 + lk * 8);
  f32x4 C[8];
#pragma unroll
  for (int nf = 0; nf < 8; ++nf) C[nf] = (f32x4){0.f, 0.f, 0.f, 0.f};
#pragma unroll
  for (int ks = 0; ks < 5; ++ks)
#pragma unroll
    for (int nf = 0; nf < 8; ++nf) {
      const s16x8 b = *(const s16x8*)(PW1m + (((ks * 4 + lk) * 128) + nf * 16 + n16) * 8);
      C[nf] = __builtin_amdgcn_mfma_f32_16x16x32_bf16(A[ks], b, C[nf], 0, 0, 0);
    }
#pragma unroll
  for (int nf = 0; nf < 8; ++nf) {
    const float bv = b1[nf * 16 + n16];
#pragma unroll
    for (int r = 0; r < 4; ++r)
      Hm[(long)(tile * 16 + lk * 4 + r) * HH + nf * 16 + n16] = C[nf][r] + bv;
  }
}

// ---------------------------------------------------------------------------
// edge_kernel: fused GEMM1 + GEMM2 + segment-max. One wave per segment,
// grid-stride. B1/B2 staged in LDS once per block; H1 lives only in a
// per-wave LDS bounce tile (bf16). No H1 global round-trip.
// ---------------------------------------------------------------------------
__global__ __launch_bounds__(512, 2) void edge_kernel(
    const unsigned short* __restrict__ tab, const short* __restrict__ PB1,
    const short* __restrict__ PB2, const float* __restrict__ W1,
    const float* __restrict__ Hm, const float* __restrict__ iou,
    const int* __restrict__ nbrIdx, const int* __restrict__ offs,
    const float* __restrict__ b2, unsigned short* __restrict__ pooled) {
  extern __shared__ __align__(16) char smem[];
  short* Bs1 = (short*)smem;                  // 40960 B
  short* Bs2 = (short*)(smem + 40960);        // 32768 B
  short* stAll = (short*)(smem + 73728);      // 8 waves * 16*136*2 B
  {
    const f32x4* s1 = (const f32x4*)PB1;
    f32x4* d1 = (f32x4*)Bs1;
    for (int i = threadIdx.x; i < 2560; i += 512) d1[i] = s1[i];
    const f32x4* s2 = (const f32x4*)PB2;
    f32x4* d2 = (f32x4*)Bs2;
    for (int i = threadIdx.x; i < 2048; i += 512) d2[i] = s2[i];
  }
  __syncthreads();

  const int lane = threadIdx.x & 63;
  const int w = threadIdx.x >> 6;
  const int lk = lane >> 4, n16 = lane & 15;
  short* st = stAll + w * (16 * 136);

  float wv[8], bv[8];
#pragma unroll
  for (int nf = 0; nf < 8; ++nf) {
    wv[nf] = W1[258 * HH + nf * 16 + n16];
    bv[nf] = b2[nf * 16 + n16];
  }

  const int wid = (blockIdx.x << 3) + w;
  const int nw = gridDim.x << 3;

  for (int seg = wid; seg < NSEG; seg += nw) {
    const int e0 = offs[seg], e1 = offs[seg + 1];
    const int nt = (e1 - e0 + 15) >> 4;
    float hmv[8];
#pragma unroll
    for (int nf = 0; nf < 8; ++nf) hmv[nf] = Hm[(long)seg * HH + nf * 16 + n16];
    float pm[8];
#pragma unroll
    for (int nf = 0; nf < 8; ++nf) pm[nf] = 0.f;

    for (int t = 0; t < nt; ++t) {
      // gather A (16 edges, clamped -> duplicates, harmless for max)
      int ea = e0 + (t << 4) + n16;
      if (ea >= e1) ea = e1 - 1;
      const unsigned short* arow = tab + (long)nbrIdx[ea] * 160;
      s16x8 A[5];
#pragma unroll
      for (int ks = 0; ks < 5; ++ks) A[ks] = *(const s16x8*)(arow + ks * 32 + lk * 8);
      float io[4];
#pragma unroll
      for (int r = 0; r < 4; ++r) {
        int e = e0 + (t << 4) + lk * 4 + r;
        io[r] = iou[e < e1 ? e : (e1 - 1)];
      }
      // GEMM1
      f32x4 C1[8];
#pragma unroll
      for (int nf = 0; nf < 8; ++nf) C1[nf] = (f32x4){0.f, 0.f, 0.f, 0.f};
#pragma unroll
      for (int ks = 0; ks < 5; ++ks)
#pragma unroll
        for (int nf = 0; nf < 8; ++nf) {
          const s16x8 b = *(const s16x8*)(Bs1 + (((ks * 4 + lk) * 128) + nf * 16 + n16) * 8);
          C1[nf] = __builtin_amdgcn_mfma_f32_16x16x32_bf16(A[ks], b, C1[nf], 0, 0, 0);
        }
      // bounce: D-layout (row=edge lk*4+r, col=nf*16+n16) -> bf16 LDS tile
#pragma unroll
      for (int nf = 0; nf < 8; ++nf)
#pragma unroll
        for (int r = 0; r < 4; ++r)
          st[(lk * 4 + r) * 136 + nf * 16 + n16] =
              (short)f2bf(fmaxf(C1[nf][r] + io[r] * wv[nf] + hmv[nf], 0.f));
      // GEMM2: A-frags from LDS (row=n16 edge, k=ks*32+lk*8)
      s16x8 A2[4];
#pragma unroll
      for (int ks = 0; ks < 4; ++ks)
        A2[ks] = *(const s16x8*)(st + n16 * 136 + ks * 32 + lk * 8);
      f32x4 C2[8];
#pragma unroll
      for (int nf = 0; nf < 8; ++nf) C2[nf] = (f32x4){0.f, 0.f, 0.f, 0.f};
#pragma unroll
      for (int ks = 0; ks < 4; ++ks)
#pragma unroll
        for (int nf = 0; nf < 8; ++nf) {
          const s16x8 b = *(const s16x8*)(Bs2 + (((ks * 4 + lk) * 128) + nf * 16 + n16) * 8);
          C2[nf] = __builtin_amdgcn_mfma_f32_16x16x32_bf16(A2[ks], b, C2[nf], 0, 0, 0);
        }
#pragma unroll
      for (int nf = 0; nf < 8; ++nf)
#pragma unroll
        for (int r = 0; r < 4; ++r) pm[nf] = fmaxf(pm[nf], C2[nf][r] + bv[nf]);
    }
#pragma unroll
    for (int nf = 0; nf < 8; ++nf) {
      float p = pm[nf];
      p = fmaxf(p, __shfl_xor(p, 16, 64));
      p = fmaxf(p, __shfl_xor(p, 32, 64));
      pm[nf] = p;
    }
    if (lane < 16) {
#pragma unroll
      for (int nf = 0; nf < 8; ++nf)
        pooled[(long)seg * HH + nf * 16 + n16] = f2bf(pm[nf]);
    }
  }
}

// ---------------------------------------------------------------------------
// resout: RES = resIn + bo + pooled @ Wo (MFMA). Then, via a bf16 LDS bounce
// of the result row:
//   NEXT=1: write resOut fp32 + TAB bf16 and compute HM_next = b1n + res@W1m.
//   NEXT=0: fused final head out = relu(res@fW1+fb1)@fW2 + fb2.
// ---------------------------------------------------------------------------
template <int NEXT>
__global__ __launch_bounds__(256) void resout_kernel(
    const unsigned short* __restrict__ pooled, const short* __restrict__ PWo,
    const float* __restrict__ bo, const float* __restrict__ resIn,
    float* __restrict__ resOut, unsigned short* __restrict__ tab,
    const short* __restrict__ PW1mN, const float* __restrict__ b1n,
    float* __restrict__ HmOut,
    const short* __restrict__ PfW1, const float* __restrict__ fb1,
    const float* __restrict__ fW2, const float* __restrict__ fb2,
    float* __restrict__ outFinal) {
  __shared__ short stS[4][16 * 168];
  const int lane = threadIdx.x & 63, w = threadIdx.x >> 6;
  const int lk = lane >> 4, n16 = lane & 15;
  short* st = stS[w];

  // zero the k-pad cols 129..160 once (A-frag reads touch up to col 159;
  // matching B rows are zero, but stale LDS NaNs would poison 0*NaN)
  {
    const int row = lane >> 2, c0 = 129 + (lane & 3) * 8;
#pragma unroll
    for (int i = 0; i < 8; ++i) st[row * 168 + c0 + i] = 0;
  }

  const int tile = blockIdx.x * 4 + w;
  const unsigned short* arow = pooled + (long)(tile * 16 + n16) * HH;
  s16x8 A[4];
#pragma unroll
  for (int ks = 0; ks < 4; ++ks) A[ks] = *(const s16x8*)(arow + ks * 32 + lk * 8);
  f32x4 C[9];
#pragma unroll
  for (int nf = 0; nf < 9; ++nf) C[nf] = (f32x4){0.f, 0.f, 0.f, 0.f};
#pragma unroll
  for (int ks = 0; ks < 4; ++ks)
#pragma unroll
    for (int nf = 0; nf < 9; ++nf) {
      const s16x8 b = *(const s16x8*)(PWo + (((ks * 4 + lk) * 144) + nf * 16 + n16) * 8);
      C[nf] = __builtin_amdgcn_mfma_f32_16x16x32_bf16(A[ks], b, C[nf], 0, 0, 0);
    }

#pragma unroll
  for (int nf = 0; nf < 8; ++nf) {
    const int col = nf * 16 + n16;
    const float bov = bo[col];
#pragma unroll
    for (int r = 0; r < 4; ++r) {
      const int row = lk * 4 + r;
      const long node = tile * 16 + row;
      const float res = resIn[node * DD + col] + bov + C[nf][r];
      if (NEXT) {
        resOut[node * DD + col] = res;
        tab[node * 160 + col] = f2bf(res);
      }
      st[row * 168 + col] = (short)f2bf(res);
    }
  }
  if (n16 == 0) {
#pragma unroll
    for (int r = 0; r < 4; ++r) {
      const int row = lk * 4 + r;
      const long node = tile * 16 + row;
      const float res = resIn[node * DD + 128] + bo[128] + C[8][r];
      if (NEXT) {
        resOut[node * DD + 128] = res;
        tab[node * 160 + 128] = f2bf(res);
      }
      st[row * 168 + 128] = (short)f2bf(res);
    }
  }

  // A-frags of res from the bounce tile (row=n16 node, k=ks*32+lk*8, pad 0)
  s16x8 A5[5];
#pragma unroll
  for (int ks = 0; ks < 5; ++ks)
    A5[ks] = *(const s16x8*)(st + n16 * 168 + ks * 32 + lk * 8);

  if (NEXT) {
    f32x4 H[8];
#pragma unroll
    for (int nf = 0; nf < 8; ++nf) H[nf] = (f32x4){0.f, 0.f, 0.f, 0.f};
#pragma unroll
    for (int ks = 0; ks < 5; ++ks)
#pragma unroll
      for (int nf = 0; nf < 8; ++nf) {
        const s16x8 b = *(const s16x8*)(PW1mN + (((ks * 4 + lk) * 128) + nf * 16 + n16) * 8);
        H[nf] = __builtin_amdgcn_mfma_f32_16x16x32_bf16(A5[ks], b, H[nf], 0, 0, 0);
      }
#pragma unroll
    for (int nf = 0; nf < 8; ++nf) {
      const float bv = b1n[nf * 16 + n16];
#pragma unroll
      for (int r = 0; r < 4; ++r)
        HmOut[(long)(tile * 16 + lk * 4 + r) * HH + nf * 16 + n16] = H[nf][r] + bv;
    }
  } else {
    f32x4 Ch[4];
#pragma unroll
    for (int nf = 0; nf < 4; ++nf) Ch[nf] = (f32x4){0.f, 0.f, 0.f, 0.f};
#pragma unroll
    for (int ks = 0; ks < 5; ++ks)
#pragma unroll
      for (int nf = 0; nf < 4; ++nf) {
        const s16x8 b = *(const s16x8*)(PfW1 + (((ks * 4 + lk) * 64) + nf * 16 + n16) * 8);
        Ch[nf] = __builtin_amdgcn_mfma_f32_16x16x32_bf16(A5[ks], b, Ch[nf], 0, 0, 0);
      }
    float b1v[4], w2v[4];
#pragma unroll
    for (int nf = 0; nf < 4; ++nf) {
      b1v[nf] = fb1[nf * 16 + n16];
      w2v[nf] = fW2[nf * 16 + n16];
    }
#pragma unroll
    for (int r = 0; r < 4; ++r) {
      float s = 0.f;
#pragma unroll
      for (int nf = 0; nf < 4; ++nf)
        s += fmaxf(Ch[nf][r] + b1v[nf], 0.f) * w2v[nf];
      s += __shfl_xor(s, 1, 64);
      s += __shfl_xor(s, 2, 64);
      s += __shfl_xor(s, 4, 64);
      s += __shfl_xor(s, 8, 64);
      if (n16 == 0) outFinal[tile * 16 + lk * 4 + r] = s + fb2[0];
    }
  }
}

// ---------------------------------------------------------------------------
extern "C" void kernel_launch(void* const* d_in, const int* in_sizes, int n_in,
                              void* d_out, int out_size, void* d_ws, size_t ws_size,
                              hipStream_t stream) {
  const float* interp  = (const float*)d_in[0];
  const float* addInfo = (const float*)d_in[1];
  const int* sizes     = (const int*)d_in[2];
  const int* nbrIdx    = (const int*)d_in[3];
  const float* b0W1 = (const float*)d_in[5];
  const float* b0b1 = (const float*)d_in[6];
  const float* b0W2 = (const float*)d_in[7];
  const float* b0b2 = (const float*)d_in[8];
  const float* b0Wo = (const float*)d_in[9];
  const float* b0bo = (const float*)d_in[10];
  const float* b1W1 = (const float*)d_in[11];
  const float* b1b1 = (const float*)d_in[12];
  const float* b1W2 = (const float*)d_in[13];
  const float* b1b2 = (const float*)d_in[14];
  const float* b1Wo = (const float*)d_in[15];
  const float* b1bo = (const float*)d_in[16];
  const float* fW1  = (const float*)d_in[17];
  const float* fb1  = (const float*)d_in[18];
  const float* fW2  = (const float*)d_in[19];
  const float* fb2  = (const float*)d_in[20];

  char* ws = (char*)d_ws;
  int*            offs  = (int*)(ws + 0);                    // 65536
  short*          PB1   = (short*)(ws + 65536);              // 81920
  short*          PB2   = (short*)(ws + 147456);             // 65536
  short*          PWo   = (short*)(ws + 212992);             // 73728
  short*          PW1m  = (short*)(ws + 286720);             // 81920
  short*          PfW1  = (short*)(ws + 368640);             // 20480 -> pad
  unsigned short* TAB   = (unsigned short*)(ws + 393216);    // N*160*2
  float*          HM    = (float*)(ws + 5472256);            // N*128*4
  unsigned short* POOLED= (unsigned short*)(ws + 13598720);  // N*128*2
  float*          RES   = (float*)(ws + 17661952);           // N*129*4

  const int prep_blocks = 1 + (PACK_IDS / 256) + (TAB_IDS / 256);  // 10553
  prep_all_kernel<<<prep_blocks, 256, 0, stream>>>(
      sizes, offs, interp, TAB, b0W1, b1W1, b0W2, b1W2, b0Wo, b1Wo, fW1,
      PB1, PB2, PWo, PW1m, PfW1);

  const size_t e_lds = 40960 + 32768 + 8 * 16 * 136 * 2;  // 108544

  // ---- block 0 ----
  hmprep_kernel<<<NTILE / 4, 256, 0, stream>>>(TAB, PW1m, b0b1, HM);
  edge_kernel<<<256, 512, e_lds, stream>>>(TAB, PB1, PB2, b0W1, HM, addInfo,
                                           nbrIdx, offs, b0b2, POOLED);
  resout_kernel<1><<<NTILE / 4, 256, 0, stream>>>(
      POOLED, PWo, b0bo, interp, RES, TAB, PW1m + 20480, b1b1, HM,
      nullptr, nullptr, nullptr, nullptr, nullptr);

  // ---- block 1 ----
  edge_kernel<<<256, 512, e_lds, stream>>>(TAB, PB1 + 20480, PB2 + 16384, b1W1,
                                           HM, addInfo, nbrIdx, offs, b1b2,
                                           POOLED);
  resout_kernel<0><<<NTILE / 4, 256, 0, stream>>>(
      POOLED, PWo + 18432, b1bo, RES, nullptr, nullptr, nullptr, nullptr,
      nullptr, PfW1, fb1, fW2, fb2, (float*)d_out);
}

// Round 7
// 244.728 us; speedup vs baseline: 4.3437x; 1.0792x over previous
//
#include <hip/hip_runtime.h>

#define NSEG 15872
#define DD 129
#define HH 128
#define NTILE (NSEG / 16)  // 992 node tiles

typedef __attribute__((ext_vector_type(8))) short s16x8;
typedef __attribute__((ext_vector_type(4))) float f32x4;

__device__ __forceinline__ unsigned short f2bf(float x) {
  union { float f; unsigned u; } c; c.f = x;
  unsigned r = c.u + 0x7FFFu + ((c.u >> 16) & 1u);
  return (unsigned short)(r >> 16);
}

// ---------------------------------------------------------------------------
// Generic MFMA B-fragment packer: out[(g*N + n)*8 + i] =
//   bf16(W[(rowBase + g*8+i)*ld + n])  (0 outside kLimit/ncols)
// ---------------------------------------------------------------------------
__device__ __forceinline__ void packB(short* out, int idx, const float* W,
                                      int N, int ld, int ncols, int kLimit,
                                      int rowBase) {
  const int i = idx & 7;
  const int n = (idx >> 3) % N;
  const int g = idx / (8 * N);
  const int row = g * 8 + i;
  float v = 0.f;
  if (row < kLimit && n < ncols) v = W[(long)(rowBase + row) * ld + n];
  out[idx] = (short)f2bf(v);
}

// ---------------------------------------------------------------------------
// prep_all: block 0 = scan; blocks 1..632 = weight packing; rest = bf16 TAB.
// ---------------------------------------------------------------------------
#define PACK_IDS 161792  // 40960+32768+36864+40960+10240
#define TAB_IDS (NSEG * 160)
__global__ __launch_bounds__(256) void prep_all_kernel(
    const int* __restrict__ sizes, int* __restrict__ offs,
    const float* __restrict__ interp, unsigned short* __restrict__ tab,
    const float* __restrict__ W1b0, const float* __restrict__ W1b1,
    const float* __restrict__ W2b0, const float* __restrict__ W2b1,
    const float* __restrict__ Wob0, const float* __restrict__ Wob1,
    const float* __restrict__ fW1, short* __restrict__ PB1,
    short* __restrict__ PB2, short* __restrict__ PWo,
    short* __restrict__ PW1m, short* __restrict__ PfW1) {
  if (blockIdx.x == 0) {
    __shared__ int sums[256];
    __shared__ int pref[256];
    const int t = threadIdx.x;
    const int chunk = (NSEG + 255) >> 8;
    const int s0 = t * chunk, s1 = min(s0 + chunk, NSEG);
    int s = 0;
    for (int i = s0; i < s1; ++i) s += sizes[i];
    sums[t] = s;
    __syncthreads();
    if (t == 0) { int a = 0; for (int i = 0; i < 256; ++i) { pref[i] = a; a += sums[i]; } }
    __syncthreads();
    int a = pref[t];
    for (int i = s0; i < s1; ++i) { offs[i] = a; a += sizes[i]; }
    if (t == 255) offs[NSEG] = a;
    return;
  }
  int id = (blockIdx.x - 1) * 256 + threadIdx.x;
  if (id < PACK_IDS) {
    if (id < 40960) {  // W1 neighbor half, K 129->160, N 128
      packB(PB1 + (id / 20480) * 20480, id % 20480, (id < 20480) ? W1b0 : W1b1,
            128, 128, 128, 129, 0);
      return;
    }
    id -= 40960;
    if (id < 32768) {  // W2, K 128, N 128
      packB(PB2 + (id / 16384) * 16384, id % 16384, (id < 16384) ? W2b0 : W2b1,
            128, 128, 128, 128, 0);
      return;
    }
    id -= 32768;
    if (id < 36864) {  // Wo, K 128, N 129->144
      packB(PWo + (id / 18432) * 18432, id % 18432, (id < 18432) ? Wob0 : Wob1,
            144, 129, 129, 128, 0);
      return;
    }
    id -= 36864;
    if (id < 40960) {  // W1 main half (rows 129..257), K 129->160, N 128
      packB(PW1m + (id / 20480) * 20480, id % 20480, (id < 20480) ? W1b0 : W1b1,
            128, 128, 128, 129, 129);
      return;
    }
    id -= 40960;
    packB(PfW1, id, fW1, 64, 64, 64, 129, 0);  // fW1 K 129->160, N 64
    return;
  }
  id -= PACK_IDS;
  if (id < TAB_IDS) {
    const int n = id / 160, k = id - n * 160;
    tab[id] = (k < DD) ? f2bf(interp[(long)n * DD + k]) : (unsigned short)0;
  }
}

// ---------------------------------------------------------------------------
// HM = b1 + tab @ W1main  (dense MFMA over 16-node tiles; block-0 only)
// ---------------------------------------------------------------------------
__global__ __launch_bounds__(256) void hmprep_kernel(
    const unsigned short* __restrict__ tab, const short* __restrict__ PW1m,
    const float* __restrict__ b1, float* __restrict__ Hm) {
  const int lane = threadIdx.x & 63, w = threadIdx.x >> 6;
  const int lk = lane >> 4, n16 = lane & 15;
  const int tile = blockIdx.x * 4 + w;
  const unsigned short* arow = tab + (long)(tile * 16 + n16) * 160;
  s16x8 A[5];
#pragma unroll
  for (int ks = 0; ks < 5; ++ks) A[ks] = *(const s16x8*)(arow + ks * 32 + lk * 8);
  f32x4 C[8];
#pragma unroll
  for (int nf = 0; nf < 8; ++nf) C[nf] = (f32x4){0.f, 0.f, 0.f, 0.f};
#pragma unroll
  for (int ks = 0; ks < 5; ++ks)
#pragma unroll
    for (int nf = 0; nf < 8; ++nf) {
      const s16x8 b = *(const s16x8*)(PW1m + (((ks * 4 + lk) * 128) + nf * 16 + n16) * 8);
      C[nf] = __builtin_amdgcn_mfma_f32_16x16x32_bf16(A[ks], b, C[nf], 0, 0, 0);
    }
#pragma unroll
  for (int nf = 0; nf < 8; ++nf) {
    const float bv = b1[nf * 16 + n16];
#pragma unroll
    for (int r = 0; r < 4; ++r)
      Hm[(long)(tile * 16 + lk * 4 + r) * HH + nf * 16 + n16] = C[nf][r] + bv;
  }
}

// ---------------------------------------------------------------------------
// edge_kernel: fused GEMM1 + GEMM2 + segment-max, TWO segments per wave in
// lockstep (slots A/B). Each LDS B-fragment read feeds two MFMAs -> halves
// the LDS bandwidth per MFMA (the R6 bottleneck) and doubles the independent
// chains hiding gather latency. Shorter slot clamps to its last edge
// (duplicates are harmless under max).
// ---------------------------------------------------------------------------
__global__ __launch_bounds__(512, 2) void edge_kernel(
    const unsigned short* __restrict__ tab, const short* __restrict__ PB1,
    const short* __restrict__ PB2, const float* __restrict__ W1,
    const float* __restrict__ Hm, const float* __restrict__ iou,
    const int* __restrict__ nbrIdx, const int* __restrict__ offs,
    const float* __restrict__ b2, unsigned short* __restrict__ pooled) {
  extern __shared__ __align__(16) char smem[];
  short* Bs1 = (short*)smem;                  // 40960 B
  short* Bs2 = (short*)(smem + 40960);        // 32768 B
  short* stAll = (short*)(smem + 73728);      // 8 waves * 2 * 16*136*2 B
  {
    const f32x4* s1 = (const f32x4*)PB1;
    f32x4* d1 = (f32x4*)Bs1;
    for (int i = threadIdx.x; i < 2560; i += 512) d1[i] = s1[i];
    const f32x4* s2 = (const f32x4*)PB2;
    f32x4* d2 = (f32x4*)Bs2;
    for (int i = threadIdx.x; i < 2048; i += 512) d2[i] = s2[i];
  }
  __syncthreads();

  const int lane = threadIdx.x & 63;
  const int w = threadIdx.x >> 6;
  const int lk = lane >> 4, n16 = lane & 15;
  short* stA = stAll + w * 2 * (16 * 136);
  short* stB = stA + 16 * 136;

  float wv[8], bv[8];
#pragma unroll
  for (int nf = 0; nf < 8; ++nf) {
    wv[nf] = W1[258 * HH + nf * 16 + n16];
    bv[nf] = b2[nf * 16 + n16];
  }

  const int wid = (blockIdx.x << 3) + w;
  const int nw = gridDim.x << 3;

  for (int s = wid; s < NSEG; s += 2 * nw) {
    const int segA = s;
    int segB = s + nw;
    if (segB >= NSEG) segB = segA;  // duplicate slot (benign)
    const int a0 = offs[segA], a1 = offs[segA + 1];
    const int b0 = offs[segB], b1 = offs[segB + 1];
    const int ntA = (a1 - a0 + 15) >> 4, ntB = (b1 - b0 + 15) >> 4;
    const int nt = max(ntA, ntB);

    float hmA[8], hmB[8], pmA[8], pmB[8];
#pragma unroll
    for (int nf = 0; nf < 8; ++nf) {
      hmA[nf] = Hm[(long)segA * HH + nf * 16 + n16];
      hmB[nf] = Hm[(long)segB * HH + nf * 16 + n16];
      pmA[nf] = 0.f;
      pmB[nf] = 0.f;
    }

    for (int t = 0; t < nt; ++t) {
      // gathers for both slots (clamped -> duplicate edges, harmless)
      int eA = a0 + (t << 4) + n16; if (eA >= a1) eA = a1 - 1;
      int eB = b0 + (t << 4) + n16; if (eB >= b1) eB = b1 - 1;
      const unsigned short* rA = tab + (long)nbrIdx[eA] * 160;
      const unsigned short* rB = tab + (long)nbrIdx[eB] * 160;
      s16x8 AA[5], AB[5];
#pragma unroll
      for (int ks = 0; ks < 5; ++ks) {
        AA[ks] = *(const s16x8*)(rA + ks * 32 + lk * 8);
        AB[ks] = *(const s16x8*)(rB + ks * 32 + lk * 8);
      }
      float ioA[4], ioB[4];
#pragma unroll
      for (int r = 0; r < 4; ++r) {
        int ea = a0 + (t << 4) + lk * 4 + r;
        int eb = b0 + (t << 4) + lk * 4 + r;
        ioA[r] = iou[ea < a1 ? ea : (a1 - 1)];
        ioB[r] = iou[eb < b1 ? eb : (b1 - 1)];
      }
      // GEMM1 (B read once, two MFMAs)
      f32x4 C1A[8], C1B[8];
#pragma unroll
      for (int nf = 0; nf < 8; ++nf) {
        C1A[nf] = (f32x4){0.f, 0.f, 0.f, 0.f};
        C1B[nf] = (f32x4){0.f, 0.f, 0.f, 0.f};
      }
#pragma unroll
      for (int ks = 0; ks < 5; ++ks)
#pragma unroll
        for (int nf = 0; nf < 8; ++nf) {
          const s16x8 b = *(const s16x8*)(Bs1 + (((ks * 4 + lk) * 128) + nf * 16 + n16) * 8);
          C1A[nf] = __builtin_amdgcn_mfma_f32_16x16x32_bf16(AA[ks], b, C1A[nf], 0, 0, 0);
          C1B[nf] = __builtin_amdgcn_mfma_f32_16x16x32_bf16(AB[ks], b, C1B[nf], 0, 0, 0);
        }
      // bounce both tiles: D-layout -> bf16 LDS
#pragma unroll
      for (int nf = 0; nf < 8; ++nf)
#pragma unroll
        for (int r = 0; r < 4; ++r) {
          stA[(lk * 4 + r) * 136 + nf * 16 + n16] =
              (short)f2bf(fmaxf(C1A[nf][r] + ioA[r] * wv[nf] + hmA[nf], 0.f));
          stB[(lk * 4 + r) * 136 + nf * 16 + n16] =
              (short)f2bf(fmaxf(C1B[nf][r] + ioB[r] * wv[nf] + hmB[nf], 0.f));
        }
      // GEMM2 A-frags from LDS (row=n16 edge, k=ks*32+lk*8)
      s16x8 A2A[4], A2B[4];
#pragma unroll
      for (int ks = 0; ks < 4; ++ks) {
        A2A[ks] = *(const s16x8*)(stA + n16 * 136 + ks * 32 + lk * 8);
        A2B[ks] = *(const s16x8*)(stB + n16 * 136 + ks * 32 + lk * 8);
      }
      f32x4 C2A[8], C2B[8];
#pragma unroll
      for (int nf = 0; nf < 8; ++nf) {
        C2A[nf] = (f32x4){0.f, 0.f, 0.f, 0.f};
        C2B[nf] = (f32x4){0.f, 0.f, 0.f, 0.f};
      }
#pragma unroll
      for (int ks = 0; ks < 4; ++ks)
#pragma unroll
        for (int nf = 0; nf < 8; ++nf) {
          const s16x8 b = *(const s16x8*)(Bs2 + (((ks * 4 + lk) * 128) + nf * 16 + n16) * 8);
          C2A[nf] = __builtin_amdgcn_mfma_f32_16x16x32_bf16(A2A[ks], b, C2A[nf], 0, 0, 0);
          C2B[nf] = __builtin_amdgcn_mfma_f32_16x16x32_bf16(A2B[ks], b, C2B[nf], 0, 0, 0);
        }
#pragma unroll
      for (int nf = 0; nf < 8; ++nf)
#pragma unroll
        for (int r = 0; r < 4; ++r) {
          pmA[nf] = fmaxf(pmA[nf], C2A[nf][r] + bv[nf]);
          pmB[nf] = fmaxf(pmB[nf], C2B[nf][r] + bv[nf]);
        }
    }
#pragma unroll
    for (int nf = 0; nf < 8; ++nf) {
      float pa = pmA[nf], pb = pmB[nf];
      pa = fmaxf(pa, __shfl_xor(pa, 16, 64));
      pa = fmaxf(pa, __shfl_xor(pa, 32, 64));
      pb = fmaxf(pb, __shfl_xor(pb, 16, 64));
      pb = fmaxf(pb, __shfl_xor(pb, 32, 64));
      pmA[nf] = pa;
      pmB[nf] = pb;
    }
    if (lane < 16) {
#pragma unroll
      for (int nf = 0; nf < 8; ++nf) {
        pooled[(long)segA * HH + nf * 16 + n16] = f2bf(pmA[nf]);
        pooled[(long)segB * HH + nf * 16 + n16] = f2bf(pmB[nf]);
      }
    }
  }
}

// ---------------------------------------------------------------------------
// resout: RES = resIn + bo + pooled @ Wo (MFMA). Then, via a bf16 LDS bounce
// of the result row:
//   NEXT=1: write resOut fp32 + TAB bf16 and compute HM_next = b1n + res@W1m.
//   NEXT=0: fused final head out = relu(res@fW1+fb1)@fW2 + fb2.
// ---------------------------------------------------------------------------
template <int NEXT>
__global__ __launch_bounds__(256) void resout_kernel(
    const unsigned short* __restrict__ pooled, const short* __restrict__ PWo,
    const float* __restrict__ bo, const float* __restrict__ resIn,
    float* __restrict__ resOut, unsigned short* __restrict__ tab,
    const short* __restrict__ PW1mN, const float* __restrict__ b1n,
    float* __restrict__ HmOut,
    const short* __restrict__ PfW1, const float* __restrict__ fb1,
    const float* __restrict__ fW2, const float* __restrict__ fb2,
    float* __restrict__ outFinal) {
  __shared__ short stS[4][16 * 168];
  const int lane = threadIdx.x & 63, w = threadIdx.x >> 6;
  const int lk = lane >> 4, n16 = lane & 15;
  short* st = stS[w];

  // zero the k-pad cols 129..160 once (A-frag reads touch up to col 159)
  {
    const int row = lane >> 2, c0 = 129 + (lane & 3) * 8;
#pragma unroll
    for (int i = 0; i < 8; ++i) st[row * 168 + c0 + i] = 0;
  }

  const int tile = blockIdx.x * 4 + w;
  const unsigned short* arow = pooled + (long)(tile * 16 + n16) * HH;
  s16x8 A[4];
#pragma unroll
  for (int ks = 0; ks < 4; ++ks) A[ks] = *(const s16x8*)(arow + ks * 32 + lk * 8);
  f32x4 C[9];
#pragma unroll
  for (int nf = 0; nf < 9; ++nf) C[nf] = (f32x4){0.f, 0.f, 0.f, 0.f};
#pragma unroll
  for (int ks = 0; ks < 4; ++ks)
#pragma unroll
    for (int nf = 0; nf < 9; ++nf) {
      const s16x8 b = *(const s16x8*)(PWo + (((ks * 4 + lk) * 144) + nf * 16 + n16) * 8);
      C[nf] = __builtin_amdgcn_mfma_f32_16x16x32_bf16(A[ks], b, C[nf], 0, 0, 0);
    }

#pragma unroll
  for (int nf = 0; nf < 8; ++nf) {
    const int col = nf * 16 + n16;
    const float bov = bo[col];
#pragma unroll
    for (int r = 0; r < 4; ++r) {
      const int row = lk * 4 + r;
      const long node = tile * 16 + row;
      const float res = resIn[node * DD + col] + bov + C[nf][r];
      if (NEXT) {
        resOut[node * DD + col] = res;
        tab[node * 160 + col] = f2bf(res);
      }
      st[row * 168 + col] = (short)f2bf(res);
    }
  }
  if (n16 == 0) {
#pragma unroll
    for (int r = 0; r < 4; ++r) {
      const int row = lk * 4 + r;
      const long node = tile * 16 + row;
      const float res = resIn[node * DD + 128] + bo[128] + C[8][r];
      if (NEXT) {
        resOut[node * DD + 128] = res;
        tab[node * 160 + 128] = f2bf(res);
      }
      st[row * 168 + 128] = (short)f2bf(res);
    }
  }

  // A-frags of res from the bounce tile (row=n16 node, k=ks*32+lk*8, pad 0)
  s16x8 A5[5];
#pragma unroll
  for (int ks = 0; ks < 5; ++ks)
    A5[ks] = *(const s16x8*)(st + n16 * 168 + ks * 32 + lk * 8);

  if (NEXT) {
    f32x4 H[8];
#pragma unroll
    for (int nf = 0; nf < 8; ++nf) H[nf] = (f32x4){0.f, 0.f, 0.f, 0.f};
#pragma unroll
    for (int ks = 0; ks < 5; ++ks)
#pragma unroll
      for (int nf = 0; nf < 8; ++nf) {
        const s16x8 b = *(const s16x8*)(PW1mN + (((ks * 4 + lk) * 128) + nf * 16 + n16) * 8);
        H[nf] = __builtin_amdgcn_mfma_f32_16x16x32_bf16(A5[ks], b, H[nf], 0, 0, 0);
      }
#pragma unroll
    for (int nf = 0; nf < 8; ++nf) {
      const float bv = b1n[nf * 16 + n16];
#pragma unroll
      for (int r = 0; r < 4; ++r)
        HmOut[(long)(tile * 16 + lk * 4 + r) * HH + nf * 16 + n16] = H[nf][r] + bv;
    }
  } else {
    f32x4 Ch[4];
#pragma unroll
    for (int nf = 0; nf < 4; ++nf) Ch[nf] = (f32x4){0.f, 0.f, 0.f, 0.f};
#pragma unroll
    for (int ks = 0; ks < 5; ++ks)
#pragma unroll
      for (int nf = 0; nf < 4; ++nf) {
        const s16x8 b = *(const s16x8*)(PfW1 + (((ks * 4 + lk) * 64) + nf * 16 + n16) * 8);
        Ch[nf] = __builtin_amdgcn_mfma_f32_16x16x32_bf16(A5[ks], b, Ch[nf], 0, 0, 0);
      }
    float b1v[4], w2v[4];
#pragma unroll
    for (int nf = 0; nf < 4; ++nf) {
      b1v[nf] = fb1[nf * 16 + n16];
      w2v[nf] = fW2[nf * 16 + n16];
    }
#pragma unroll
    for (int r = 0; r < 4; ++r) {
      float s = 0.f;
#pragma unroll
      for (int nf = 0; nf < 4; ++nf)
        s += fmaxf(Ch[nf][r] + b1v[nf], 0.f) * w2v[nf];
      s += __shfl_xor(s, 1, 64);
      s += __shfl_xor(s, 2, 64);
      s += __shfl_xor(s, 4, 64);
      s += __shfl_xor(s, 8, 64);
      if (n16 == 0) outFinal[tile * 16 + lk * 4 + r] = s + fb2[0];
    }
  }
}

// ---------------------------------------------------------------------------
extern "C" void kernel_launch(void* const* d_in, const int* in_sizes, int n_in,
                              void* d_out, int out_size, void* d_ws, size_t ws_size,
                              hipStream_t stream) {
  const float* interp  = (const float*)d_in[0];
  const float* addInfo = (const float*)d_in[1];
  const int* sizes     = (const int*)d_in[2];
  const int* nbrIdx    = (const int*)d_in[3];
  const float* b0W1 = (const float*)d_in[5];
  const float* b0b1 = (const float*)d_in[6];
  const float* b0W2 = (const float*)d_in[7];
  const float* b0b2 = (const float*)d_in[8];
  const float* b0Wo = (const float*)d_in[9];
  const float* b0bo = (const float*)d_in[10];
  const float* b1W1 = (const float*)d_in[11];
  const float* b1b1 = (const float*)d_in[12];
  const float* b1W2 = (const float*)d_in[13];
  const float* b1b2 = (const float*)d_in[14];
  const float* b1Wo = (const float*)d_in[15];
  const float* b1bo = (const float*)d_in[16];
  const float* fW1  = (const float*)d_in[17];
  const float* fb1  = (const float*)d_in[18];
  const float* fW2  = (const float*)d_in[19];
  const float* fb2  = (const float*)d_in[20];

  char* ws = (char*)d_ws;
  int*            offs  = (int*)(ws + 0);                    // 65536
  short*          PB1   = (short*)(ws + 65536);              // 81920
  short*          PB2   = (short*)(ws + 147456);             // 65536
  short*          PWo   = (short*)(ws + 212992);             // 73728
  short*          PW1m  = (short*)(ws + 286720);             // 81920
  short*          PfW1  = (short*)(ws + 368640);             // 20480 -> pad
  unsigned short* TAB   = (unsigned short*)(ws + 393216);    // N*160*2
  float*          HM    = (float*)(ws + 5472256);            // N*128*4
  unsigned short* POOLED= (unsigned short*)(ws + 13598720);  // N*128*2
  float*          RES   = (float*)(ws + 17661952);           // N*129*4

  const int prep_blocks = 1 + (PACK_IDS / 256) + (TAB_IDS / 256);  // 10553
  prep_all_kernel<<<prep_blocks, 256, 0, stream>>>(
      sizes, offs, interp, TAB, b0W1, b1W1, b0W2, b1W2, b0Wo, b1Wo, fW1,
      PB1, PB2, PWo, PW1m, PfW1);

  const size_t e_lds = 40960 + 32768 + 8 * 2 * 16 * 136 * 2;  // 143360

  // ---- block 0 ----
  hmprep_kernel<<<NTILE / 4, 256, 0, stream>>>(TAB, PW1m, b0b1, HM);
  edge_kernel<<<256, 512, e_lds, stream>>>(TAB, PB1, PB2, b0W1, HM, addInfo,
                                           nbrIdx, offs, b0b2, POOLED);
  resout_kernel<1><<<NTILE / 4, 256, 0, stream>>>(
      POOLED, PWo, b0bo, interp, RES, TAB, PW1m + 20480, b1b1, HM,
      nullptr, nullptr, nullptr, nullptr, nullptr);

  // ---- block 1 ----
  edge_kernel<<<256, 512, e_lds, stream>>>(TAB, PB1 + 20480, PB2 + 16384, b1W1,
                                           HM, addInfo, nbrIdx, offs, b1b2,
                                           POOLED);
  resout_kernel<0><<<NTILE / 4, 256, 0, stream>>>(
      POOLED, PWo + 18432, b1bo, RES, nullptr, nullptr, nullptr, nullptr,
      nullptr, PfW1, fb1, fW2, fb2, (float*)d_out);
}